// Round 17
// baseline (210.464 us; speedup 1.0000x reference)
//
#include <hip/hip_runtime.h>

typedef unsigned short u16;
typedef __bf16 bf16x8 __attribute__((ext_vector_type(8)));
typedef float f32x4 __attribute__((ext_vector_type(4)));
typedef short s16x4 __attribute__((ext_vector_type(4)));

#define S_LEN  2048
#define NHEADS 16
#define NKVH   4
#define HDIM   128
#define BB     2
#define MROWS  4096   // B*S
#define QKV_N  3072   // NH*HD + 2*NKV*HD
#define HID    2048

__device__ __forceinline__ u16 f2b(float f) {
  union { float f; unsigned u; } x; x.f = f;
  unsigned r = x.u + 0x7fffu + ((x.u >> 16) & 1u);
  return (u16)(r >> 16);
}
__device__ __forceinline__ float b2f(u16 v) {
  union { unsigned u; float f; } x; x.u = ((unsigned)v) << 16;
  return x.f;
}
__device__ __forceinline__ void gload_lds16(const u16* g, u16* l) {
  __builtin_amdgcn_global_load_lds((__attribute__((address_space(1))) void*)g,
                                   (__attribute__((address_space(3))) void*)l,
                                   16, 0, 0);
}
__device__ __forceinline__ unsigned cvtpk(float lo, float hi) {
  unsigned r;
  asm("v_cvt_pk_bf16_f32 %0, %1, %2" : "=v"(r) : "v"(lo), "v"(hi));
  return r;
}
#if __has_builtin(__builtin_amdgcn_mfma_f32_16x16x16bf16_1k)
__device__ __forceinline__ f32x4 mfma16(s16x4 a, s16x4 b, f32x4 c) {
  return __builtin_amdgcn_mfma_f32_16x16x16bf16_1k(a, b, c, 0, 0, 0);
}
#else
__device__ __forceinline__ f32x4 mfma16(s16x4 a, s16x4 b, f32x4 c) {
  asm("v_mfma_f32_16x16x16_bf16 %0, %1, %2, %0" : "+v"(c) : "v"(a), "v"(b));
  return c;
}
#endif

#define SBAR() do { __builtin_amdgcn_sched_barrier(0); \
                    __builtin_amdgcn_s_barrier();      \
                    __builtin_amdgcn_sched_barrier(0); } while (0)

// ---- one-launch prep: all fp32->bf16 converts + RoPE cos/sin table ----
#define PB_X   8192
#define PB_WQ  (PB_X + 4096)
#define PB_WK  (PB_WQ + 1024)
#define PB_WV  (PB_WK + 1024)
#define PB_WO  (PB_WV + 4096)
#define PB_CS  (PB_WO + 512)
__global__ void k_prep(const float* __restrict__ x,
                       const float* __restrict__ Wq, const float* __restrict__ Wk,
                       const float* __restrict__ Wv, const float* __restrict__ Wo,
                       u16* __restrict__ xb, u16* __restrict__ Wqkvb,
                       u16* __restrict__ Wob, float* __restrict__ cs)
{
  const int bid = blockIdx.x, tid = threadIdx.x;
  const float* src; u16* dst; int i;
  if (bid < PB_X)       { i = bid * 256 + tid;            src = x;  dst = xb; }
  else if (bid < PB_WQ) { i = (bid - PB_X) * 256 + tid;   src = Wq; dst = Wqkvb; }
  else if (bid < PB_WK) { i = (bid - PB_WQ) * 256 + tid;  src = Wk; dst = Wqkvb + (size_t)2048 * HID; }
  else if (bid < PB_WV) { i = (bid - PB_WK) * 256 + tid;  src = Wv; dst = Wqkvb + (size_t)2560 * HID; }
  else if (bid < PB_WO) { i = (bid - PB_WV) * 256 + tid;  src = Wo; dst = Wob; }
  else {
    const int p = (bid - PB_WO) * 256 + tid;
    const int s = p >> 6, j = p & 63;
    float inv = expf(-(float)j * 0.14391156831212787f);
    float ang = (float)s * inv;
    float c, sn; sincosf(ang, &sn, &c);
    cs[p * 2 + 0] = c; cs[p * 2 + 1] = sn;
    return;
  }
  float4 v = ((const float4*)src)[i];
  ushort4 o;
  o.x = f2b(v.x); o.y = f2b(v.y); o.z = f2b(v.z); o.w = f2b(v.w);
  ((ushort4*)dst)[i] = o;
}

// ======================================================================
// 8-phase-style 256x256 GEMM (T2 swizzle + T3/T4 counted-vmcnt + T5)
// ======================================================================
#define MFMA_GRP(AV, BV, MO, NO)                                              \
  __builtin_amdgcn_s_setprio(1);                                              \
  _Pragma("unroll") for (int kk = 0; kk < 2; ++kk)                            \
  _Pragma("unroll") for (int mm = 0; mm < 4; ++mm)                            \
  _Pragma("unroll") for (int nn = 0; nn < 2; ++nn)                            \
    acc[(MO) + mm][(NO) + nn] = __builtin_amdgcn_mfma_f32_16x16x32_bf16(      \
        AV[kk][mm], BV[kk][nn], acc[(MO) + mm][(NO) + nn], 0, 0, 0);          \
  __builtin_amdgcn_s_setprio(0);

template <int OUT_BF16>
__global__ __launch_bounds__(512, 2) void k_gemm256(
    const u16* __restrict__ A, const u16* __restrict__ Bm, void* __restrict__ Cv,
    int M, int N, int K)
{
  __shared__ u16 AL[2][2][8192];   // 64 KB
  __shared__ u16 BL[2][2][8192];   // 64 KB
  const int tid = threadIdx.x;
  const int wave = tid >> 6, lane = tid & 63;
  const int l15 = lane & 15, l4 = lane >> 4;
  const int wr = wave >> 2, wc = wave & 3;
  const int gx = gridDim.x;
  const int nwg = gx * gridDim.y;
  int bid = blockIdx.y * gx + blockIdx.x;
  bid = (bid & 7) * (nwg >> 3) + (bid >> 3);
  const int col0 = (bid % gx) * 256, row0 = (bid / gx) * 256;

  int srcOff[2], dstD[2];
#pragma unroll
  for (int li = 0; li < 2; ++li) {
    const int D = (li * 512 + tid) * 16;
    const int off_p = D & 1023, si = D >> 10;
    const int off_l = off_p ^ (((off_p >> 9) & 1) << 5);
    const int R = si >> 1, C = si & 1;
    const int row = R * 16 + (off_l >> 6);
    const int colb = C * 64 + (off_l & 63);
    srcOff[li] = row * K + (colb >> 1);
    dstD[li] = D;
  }
  const int laneoff = (l15 * 64 + l4 * 16) ^ ((l15 >> 3) << 5);

  auto stage = [&](const u16* __restrict__ G, int grow0, int kb, u16* lds) {
#pragma unroll
    for (int li = 0; li < 2; ++li)
      gload_lds16(G + (size_t)grow0 * K + kb + srcOff[li],
                  (u16*)((char*)lds + dstD[li]));
  };

  f32x4 acc[8][4];
#pragma unroll
  for (int m = 0; m < 8; ++m)
#pragma unroll
    for (int n = 0; n < 4; ++n) acc[m][n] = f32x4{0.f, 0.f, 0.f, 0.f};

  const int nk = K >> 6;
  stage(A,  row0,       0,  &AL[0][0][0]);
  stage(A,  row0 + 128, 0,  &AL[0][1][0]);
  stage(Bm, col0,       0,  &BL[0][0][0]);
  stage(Bm, col0 + 128, 0,  &BL[0][1][0]);
  stage(A,  row0,       64, &AL[1][0][0]);
  stage(A,  row0 + 128, 64, &AL[1][1][0]);
  asm volatile("s_waitcnt vmcnt(4)" ::: "memory");
  SBAR();

  for (int t = 0; t < nk; ++t) {
    const int bi = t & 1;
    const bool sB = (t + 1 < nk);
    const bool sA = (t + 2 < nk);
    const char* Ab = (const char*)&AL[bi][wr][0];
    const char* Bb = (const char*)&BL[bi][wc >> 1][0] + (wc & 1) * 8192;
    bf16x8 a0[2][4], a1[2][4], b0[2][2], b1[2][2];
#pragma unroll
    for (int kk = 0; kk < 2; ++kk)
#pragma unroll
      for (int m = 0; m < 4; ++m)
        a0[kk][m] = *(const bf16x8*)(Ab + m * 2048 + kk * 1024 + laneoff);
#pragma unroll
    for (int kk = 0; kk < 2; ++kk)
#pragma unroll
      for (int n = 0; n < 2; ++n)
        b0[kk][n] = *(const bf16x8*)(Bb + n * 2048 + kk * 1024 + laneoff);
    if (sB) stage(Bm, col0, (t + 1) * 64, &BL[bi ^ 1][0][0]);
    SBAR();
    MFMA_GRP(a0, b0, 0, 0);
    SBAR();
#pragma unroll
    for (int kk = 0; kk < 2; ++kk)
#pragma unroll
      for (int m = 0; m < 4; ++m)
        a1[kk][m] = *(const bf16x8*)(Ab + (m + 4) * 2048 + kk * 1024 + laneoff);
    if (sB) stage(Bm, col0 + 128, (t + 1) * 64, &BL[bi ^ 1][1][0]);
    SBAR();
    MFMA_GRP(a1, b0, 4, 0);
    SBAR();
#pragma unroll
    for (int kk = 0; kk < 2; ++kk)
#pragma unroll
      for (int n = 0; n < 2; ++n)
        b1[kk][n] = *(const bf16x8*)(Bb + (n + 2) * 2048 + kk * 1024 + laneoff);
    if (sA) stage(A, row0, (t + 2) * 64, &AL[bi][0][0]);
    SBAR();
    MFMA_GRP(a1, b1, 4, 2);
    SBAR();
    if (sA) {
      stage(A, row0 + 128, (t + 2) * 64, &AL[bi][1][0]);
      asm volatile("s_waitcnt vmcnt(4)" ::: "memory");
    } else if (sB) {
      asm volatile("s_waitcnt vmcnt(0)" ::: "memory");
    }
    SBAR();
    MFMA_GRP(a0, b1, 0, 2);
    SBAR();
  }

#pragma unroll
  for (int m = 0; m < 8; ++m) {
    const int r = row0 + wr * 128 + m * 16 + l4 * 4;
#pragma unroll
    for (int n = 0; n < 4; ++n) {
      const int c = col0 + wc * 64 + n * 16 + l15;
#pragma unroll
      for (int j = 0; j < 4; ++j) {
        const float v = acc[m][n][j];
        if (OUT_BF16) ((u16*)Cv)[(size_t)(r + j) * N + c] = f2b(v);
        else          ((float*)Cv)[(size_t)(r + j) * N + c] = v;
      }
    }
  }
}

// C[M][N] = A[M][K] * B[N][K]^T, 128x128 tile, BK=32, 2-phase dbuf,
// bijective XCD swizzle (nwg % 8 == 0).
template <int OUT_BF16>
__global__ __launch_bounds__(256) void k_gemm_bt(
    const u16* __restrict__ A, const u16* __restrict__ Bm, void* __restrict__ Cv,
    int M, int N, int K)
{
  __shared__ u16 Al[2][128 * 32];
  __shared__ u16 Bl[2][128 * 32];
  const int tid = threadIdx.x;
  const int wave = tid >> 6, lane = tid & 63;
  const int l15 = lane & 15, l4 = lane >> 4;
  const int wr = wave >> 1, wc = wave & 1;
  const int gx = gridDim.x;
  const int nwg = gx * gridDim.y;
  int bid = blockIdx.y * gx + blockIdx.x;
  bid = (bid & 7) * (nwg >> 3) + (bid >> 3);
  const int row0 = (bid / gx) * 128, col0 = (bid % gx) * 128;

  f32x4 zero = {0.f, 0.f, 0.f, 0.f};
  f32x4 acc[4][4];
#pragma unroll
  for (int m = 0; m < 4; ++m)
#pragma unroll
    for (int n = 0; n < 4; ++n) acc[m][n] = zero;

  const int e0 = lane * 8;
  auto stage = [&](int buf, int kb) {
#pragma unroll
    for (int it = 0; it < 2; ++it) {
      const int chunk = it * 4 + wave;
      const int e = chunk * 512 + e0;
      const int r = e >> 5, c = e & 31;
      gload_lds16(A + (size_t)(row0 + r) * K + kb + c, &Al[buf][chunk * 512]);
      gload_lds16(Bm + (size_t)(col0 + r) * K + kb + c, &Bl[buf][chunk * 512]);
    }
  };

  stage(0, 0);
  asm volatile("s_waitcnt vmcnt(0)" ::: "memory");
  SBAR();
  int cur = 0;
  for (int kb = 0; kb < K; kb += 32) {
    if (kb + 32 < K) stage(cur ^ 1, kb + 32);   // issue early; lands under MFMA
    bf16x8 af[4], bfv[4];
#pragma unroll
    for (int m = 0; m < 4; ++m)
      af[m] = *(const bf16x8*)(&Al[cur][(wr * 64 + m * 16 + l15) * 32 + l4 * 8]);
#pragma unroll
    for (int n = 0; n < 4; ++n)
      bfv[n] = *(const bf16x8*)(&Bl[cur][(wc * 64 + n * 16 + l15) * 32 + l4 * 8]);
    __builtin_amdgcn_s_setprio(1);
#pragma unroll
    for (int m = 0; m < 4; ++m)
#pragma unroll
      for (int n = 0; n < 4; ++n)
        acc[m][n] = __builtin_amdgcn_mfma_f32_16x16x32_bf16(af[m], bfv[n], acc[m][n], 0, 0, 0);
    __builtin_amdgcn_s_setprio(0);
    asm volatile("s_waitcnt vmcnt(0)" ::: "memory");
    SBAR();
    cur ^= 1;
  }
#pragma unroll
  for (int m = 0; m < 4; ++m) {
    const int r = row0 + wr * 64 + m * 16 + l4 * 4;
#pragma unroll
    for (int n = 0; n < 4; ++n) {
      const int c = col0 + wc * 64 + n * 16 + l15;
#pragma unroll
      for (int j = 0; j < 4; ++j) {
        const float v = acc[m][n][j];
        if (OUT_BF16) ((u16*)Cv)[(size_t)(r + j) * N + c] = f2b(v);
        else          ((float*)Cv)[(size_t)(r + j) * N + c] = v;
      }
    }
  }
}

// ---- fused RoPE (Q pre-scaled by scale*log2e) + K RoPE + V transpose ----
__global__ __launch_bounds__(256) void k_ropev(
    const u16* __restrict__ qkv, const float* __restrict__ cs,
    u16* __restrict__ Qr, u16* __restrict__ Kr, u16* __restrict__ Vt)
{
  const int blk = blockIdx.x;            // b*256 + (s>>3)
  const int b = blk >> 8, s0 = (blk & 255) << 3;
  const int tid = threadIdx.x;
  const float S2 = 0.08838834764831845f * 1.4426950408889634f;
#pragma unroll
  for (int p = tid; p < 1024; p += 256) {
    const int s = p >> 7, rem = p & 127, h = rem >> 3, j8 = (rem & 7) * 8;
    const int sg = s0 + s;
    const u16* src = qkv + (size_t)(b * S_LEN + sg) * QKV_N + h * 128 + j8;
    union { uint4 v; u16 u[8]; } lo, hi, olo, ohi;
    lo.v = *(const uint4*)(src);
    hi.v = *(const uint4*)(src + 64);
    const float* cp = cs + (size_t)(sg * 64 + j8) * 2;
#pragma unroll
    for (int k = 0; k < 8; ++k) {
      const float c = cp[k * 2], sn = cp[k * 2 + 1];
      const float x0 = b2f(lo.u[k]), x1 = b2f(hi.u[k]);
      olo.u[k] = f2b((x0 * c - x1 * sn) * S2);
      ohi.u[k] = f2b((x1 * c + x0 * sn) * S2);
    }
    u16* dst = Qr + ((size_t)(b * NHEADS + h) * S_LEN + sg) * HDIM + j8;
    *(uint4*)(dst) = olo.v;
    *(uint4*)(dst + 64) = ohi.v;
  }
  {
    const int p = tid;
    const int s = p >> 5, rem = p & 31, h = rem >> 3, j8 = (rem & 7) * 8;
    const int sg = s0 + s;
    const u16* src = qkv + (size_t)(b * S_LEN + sg) * QKV_N + 2048 + h * 128 + j8;
    union { uint4 v; u16 u[8]; } lo, hi, olo, ohi;
    lo.v = *(const uint4*)(src);
    hi.v = *(const uint4*)(src + 64);
    const float* cp = cs + (size_t)(sg * 64 + j8) * 2;
#pragma unroll
    for (int k = 0; k < 8; ++k) {
      const float c = cp[k * 2], sn = cp[k * 2 + 1];
      const float x0 = b2f(lo.u[k]), x1 = b2f(hi.u[k]);
      olo.u[k] = f2b(x0 * c - x1 * sn);
      ohi.u[k] = f2b(x1 * c + x0 * sn);
    }
    u16* dst = Kr + ((size_t)(b * NKVH + h) * S_LEN + sg) * HDIM + j8;
    *(uint4*)(dst) = olo.v;
    *(uint4*)(dst + 64) = ohi.v;
  }
#pragma unroll
  for (int vi = 0; vi < 2; ++vi) {
    const int idx = vi * 256 + tid, h = idx >> 7, d = idx & 127;
    union { u16 u[8]; uint4 v; } bb;
#pragma unroll
    for (int s = 0; s < 8; ++s)
      bb.u[s] = qkv[(size_t)(b * S_LEN + s0 + s) * QKV_N + 2560 + idx];
    *(uint4*)(Vt + ((size_t)(b * NKVH + h) * HDIM + d) * S_LEN + s0) = bb.v;
  }
}

// ---- flash attention v16: v15 body, 512 blocks of 512 thr -> 2 blocks/CU
// ---- = 16 waves/CU = 4/SIMD. Co-resident pair (bid, bid+256) differ in
// ---- qt-slot top bit: qt = s<16 ? s : 47-s -> iters sum to 33 on every CU.
__device__ __forceinline__ void attn_qtile(
    int qt,
    const u16* __restrict__ Q, const u16* __restrict__ Kg, const u16* __restrict__ Vg,
    u16* __restrict__ Out, int bh,
    u16* Kl0, u16* Kl1, u16* Vl0, u16* Vl1,
    const int (&ko)[2], const int (&vo)[2],
    int wave, int w4, int lane)
{
  const int l15 = lane & 15, l4 = lane >> 4;
  const int b = bh >> 4, h = bh & 15;
  const int qw0 = qt * 64 + w4 * 16;
  const u16* Qg = Q + ((size_t)bh * S_LEN + qw0) * HDIM;
  int cur = 0;

  bf16x8 qf[4];
#pragma unroll
  for (int kc = 0; kc < 4; ++kc)
    qf[kc] = *(const bf16x8*)(Qg + l15 * HDIM + kc * 32 + l4 * 8);

  f32x4 zero = {0.f, 0.f, 0.f, 0.f};
  f32x4 oacc[8];
#pragma unroll
  for (int i = 0; i < 8; ++i) oacc[i] = zero;
  float m_r = -1e30f, l_p = 0.f;   // per-lane row state for q = qw0 + l15

  const int nt = qt + 1;
  const int qg = qw0 + l15;

  for (int t = 0; t < nt; ++t) {
    const int kt = t * 64;
    u16* Vb = cur ? Vl1 : Vl0;
#pragma unroll
    for (int it = 0; it < 2; ++it)
      gload_lds16(Vg + (size_t)vo[it] + kt, Vb + (it * 8 + wave) * 512);
    const int hasNext = (t + 1 < nt);
    u16* Kn = cur ? Kl0 : Kl1;
    if (hasNext) {
#pragma unroll
      for (int it = 0; it < 2; ++it)
        gload_lds16(Kg + (size_t)(kt + 64) * HDIM + ko[it], Kn + (it * 8 + wave) * 512);
      asm volatile("s_waitcnt vmcnt(4)" ::: "memory");   // K(t) landed
    } else {
      asm volatile("s_waitcnt vmcnt(2)" ::: "memory");
    }
    SBAR();

    const char* Kb = (const char*)(cur ? Kl1 : Kl0);
    // ---- S^T = K Q^T : lane owns q=l15, k = 16n + 4*l4 + j ----
    f32x4 s[4];
#pragma unroll
    for (int n = 0; n < 4; ++n) s[n] = zero;
    __builtin_amdgcn_s_setprio(1);
#pragma unroll
    for (int n = 0; n < 4; ++n) {
      const int row = n * 16 + l15;
#pragma unroll
      for (int kc = 0; kc < 4; ++kc) {
        const int ab = (row * 256 + kc * 64 + l4 * 16) ^ ((row & 7) << 4);
        bf16x8 kf = *(const bf16x8*)(Kb + ab);
        s[n] = __builtin_amdgcn_mfma_f32_16x16x32_bf16(kf, qf[kc], s[n], 0, 0, 0);
      }
    }
    __builtin_amdgcn_s_setprio(0);
    // ---- (rare) causal mask + per-lane max over owned k ----
    float sv[4][4];
    if (kt + 63 > qw0) {
#pragma unroll
      for (int n = 0; n < 4; ++n)
#pragma unroll
        for (int j = 0; j < 4; ++j) {
          float x = s[n][j];
          if (kt + n * 16 + l4 * 4 + j > qg) x = -1e30f;
          sv[n][j] = x;
        }
    } else {
#pragma unroll
      for (int n = 0; n < 4; ++n)
#pragma unroll
        for (int j = 0; j < 4; ++j) sv[n][j] = s[n][j];
    }
    float pm = sv[0][0];
#pragma unroll
    for (int n = 0; n < 4; ++n)
#pragma unroll
      for (int j = 0; j < 4; ++j) pm = fmaxf(pm, sv[n][j]);
    // ---- defer-max ----
    if (!__all(pm <= m_r + 11.5416f)) {
      float pf = fmaxf(pm, __shfl_xor(pm, 16, 64));
      pf = fmaxf(pf, __shfl_xor(pf, 32, 64));
      const float mn = fmaxf(m_r, pf);
      const float sc = exp2f(m_r - mn);
      m_r = mn;
      l_p *= sc;
      float scq[4];
#pragma unroll
      for (int j = 0; j < 4; ++j) scq[j] = __shfl(sc, l4 * 4 + j, 64);
#pragma unroll
      for (int nd = 0; nd < 8; ++nd)
#pragma unroll
        for (int j = 0; j < 4; ++j) oacc[nd][j] *= scq[j];
    }
    // ---- P = exp2(sv - m), pack to bf16 pairs in-register ----
    union { unsigned u[2]; s16x4 v; } a[4];
#pragma unroll
    for (int n = 0; n < 4; ++n) {
      const float p0 = exp2f(sv[n][0] - m_r);
      const float p1 = exp2f(sv[n][1] - m_r);
      const float p2 = exp2f(sv[n][2] - m_r);
      const float p3 = exp2f(sv[n][3] - m_r);
      l_p += (p0 + p1) + (p2 + p3);
      a[n].u[0] = cvtpk(p0, p1);
      a[n].u[1] = cvtpk(p2, p3);
    }
    // ---- V(t) ready ----
    if (hasNext) asm volatile("s_waitcnt vmcnt(2)" ::: "memory");
    else         asm volatile("s_waitcnt vmcnt(0)" ::: "memory");
    SBAR();
    // ---- O += P V ----
    __builtin_amdgcn_s_setprio(1);
#pragma unroll
    for (int nd = 0; nd < 8; ++nd) {
      const int d = nd * 16 + l15;
      const int rowb = d * 128, swz = (d & 7) << 4;
#pragma unroll
      for (int n = 0; n < 4; ++n) {
        const int ab = (rowb + n * 32 + l4 * 8) ^ swz;
        s16x4 vf = *(const s16x4*)((const char*)Vb + ab);
        oacc[nd] = mfma16(a[n].v, vf, oacc[nd]);
      }
    }
    __builtin_amdgcn_s_setprio(0);
    cur ^= 1;
  }

  // ---- epilogue ----
  l_p += __shfl_xor(l_p, 16, 64);
  l_p += __shfl_xor(l_p, 32, 64);
  float il[4];
#pragma unroll
  for (int j = 0; j < 4; ++j) il[j] = 1.f / __shfl(l_p, l4 * 4 + j, 64);
  const size_t obase = ((size_t)b * S_LEN + qw0 + l4 * 4) * HID + h * HDIM;
#pragma unroll
  for (int nd = 0; nd < 8; ++nd)
#pragma unroll
    for (int j = 0; j < 4; ++j)
      Out[obase + (size_t)j * HID + nd * 16 + l15] = f2b(oacc[nd][j] * il[j]);
}

__global__ __launch_bounds__(512) void k_attn(
    const u16* __restrict__ Q, const u16* __restrict__ Kr,
    const u16* __restrict__ Vt, u16* __restrict__ Out)
{
  __shared__ u16 Kl[2][64 * 128];   // 32 KB dbuf, XOR ^((kv&7)<<4)
  __shared__ u16 Vl[2][128 * 64];   // 32 KB dbuf, XOR ^((d&7)<<4)
  const int tid = threadIdx.x;
  const int wave = tid >> 6, lane = tid & 63;
  const int bid = blockIdx.x;             // [2:0]=(b,kvh) [3]=hpair [8:4]=slot
  const int kvh = bid & 3, b = (bid >> 2) & 1;
  const int hpair = (bid >> 3) & 1;
  const int s_ = bid >> 4;                // 0..31
  const int qt = (s_ < 16) ? s_ : 47 - s_;   // pair (s, s+16) -> qt (s, 31-s)
  const int h = kvh * 4 + hpair + (wave >> 2) * 2;   // waves 0-3: h, 4-7: h+2
  const int bh = b * NHEADS + h;
  const int w4 = wave & 3;

  const u16* Kg = Kr + (size_t)(b * NKVH + kvh) * S_LEN * HDIM;
  const u16* Vg = Vt + (size_t)(b * NKVH + kvh) * HDIM * S_LEN;

  // staging offsets (rule 21): 16 chunks of 1 KB, c = it*8 + wave
  int ko[2], vo[2];
#pragma unroll
  for (int it = 0; it < 2; ++it) {
    const int c = it * 8 + wave;
    const int L = c * 1024 + lane * 16;
    const int r = L >> 8;  const int w2 = (L & 255) ^ ((r & 7) << 4);
    ko[it] = r * HDIM + (w2 >> 1);
    const int d = L >> 7;  const int wv = (L & 127) ^ ((d & 7) << 4);
    vo[it] = d * S_LEN + (wv >> 1);
  }
#pragma unroll
  for (int it = 0; it < 2; ++it)
    gload_lds16(Kg + ko[it], &Kl[0][(it * 8 + wave) * 512]);

  attn_qtile(qt, Q, Kg, Vg, Out, bh, &Kl[0][0], &Kl[1][0],
             &Vl[0][0], &Vl[1][0], ko, vo, wave, w4, lane);
}

extern "C" void kernel_launch(void* const* d_in, const int* in_sizes, int n_in,
                              void* d_out, int out_size, void* d_ws, size_t ws_size,
                              hipStream_t stream)
{
  const float* x  = (const float*)d_in[0];
  const float* Wq = (const float*)d_in[2];
  const float* Wk = (const float*)d_in[3];
  const float* Wv = (const float*)d_in[4];
  const float* Wo = (const float*)d_in[5];
  float* out = (float*)d_out;

  u16* xb    = (u16*)d_ws;
  u16* Wqkvb = xb    + (size_t)MROWS * HID;
  u16* Wob   = Wqkvb + (size_t)QKV_N * HID;
  u16* qkv   = Wob   + (size_t)HID * HID;
  u16* Qr    = qkv   + (size_t)MROWS * QKV_N;
  u16* Kr    = Qr    + (size_t)BB * NHEADS * S_LEN * HDIM;
  u16* Vt    = Kr    + (size_t)BB * NKVH * S_LEN * HDIM;
  u16* attn  = Vt    + (size_t)BB * NKVH * S_LEN * HDIM;
  float* cs  = (float*)(attn + (size_t)MROWS * HID);

  k_prep<<<dim3(PB_CS), 256, 0, stream>>>(x, Wq, Wk, Wv, Wo, xb, Wqkvb, Wob, cs);
  k_gemm256<1><<<dim3(QKV_N / 256, MROWS / 256), 512, 0, stream>>>(xb, Wqkvb, qkv, MROWS, QKV_N, HID);
  k_ropev<<<dim3(BB * 256), 256, 0, stream>>>(qkv, cs, Qr, Kr, Vt);
  k_attn<<<dim3(512), 512, 0, stream>>>(Qr, Kr, Vt, attn);
  k_gemm_bt<0><<<dim3(HID / 128, MROWS / 128), 256, 0, stream>>>(attn, Wob, out, MROWS, HID, HID);
}

// Round 18
// 206.361 us; speedup vs baseline: 1.0199x; 1.0199x over previous
//
#include <hip/hip_runtime.h>

typedef unsigned short u16;
typedef __bf16 bf16x8 __attribute__((ext_vector_type(8)));
typedef float f32x4 __attribute__((ext_vector_type(4)));
typedef short s16x4 __attribute__((ext_vector_type(4)));

#define S_LEN  2048
#define NHEADS 16
#define NKVH   4
#define HDIM   128
#define BB     2
#define MROWS  4096   // B*S
#define QKV_N  3072   // NH*HD + 2*NKV*HD
#define HID    2048

__device__ __forceinline__ u16 f2b(float f) {
  union { float f; unsigned u; } x; x.f = f;
  unsigned r = x.u + 0x7fffu + ((x.u >> 16) & 1u);
  return (u16)(r >> 16);
}
__device__ __forceinline__ float b2f(u16 v) {
  union { unsigned u; float f; } x; x.u = ((unsigned)v) << 16;
  return x.f;
}
__device__ __forceinline__ void gload_lds16(const u16* g, u16* l) {
  __builtin_amdgcn_global_load_lds((__attribute__((address_space(1))) void*)g,
                                   (__attribute__((address_space(3))) void*)l,
                                   16, 0, 0);
}
__device__ __forceinline__ unsigned cvtpk(float lo, float hi) {
  unsigned r;
  asm("v_cvt_pk_bf16_f32 %0, %1, %2" : "=v"(r) : "v"(lo), "v"(hi));
  return r;
}
#if __has_builtin(__builtin_amdgcn_mfma_f32_16x16x16bf16_1k)
__device__ __forceinline__ f32x4 mfma16(s16x4 a, s16x4 b, f32x4 c) {
  return __builtin_amdgcn_mfma_f32_16x16x16bf16_1k(a, b, c, 0, 0, 0);
}
#else
__device__ __forceinline__ f32x4 mfma16(s16x4 a, s16x4 b, f32x4 c) {
  asm("v_mfma_f32_16x16x16_bf16 %0, %1, %2, %0" : "+v"(c) : "v"(a), "v"(b));
  return c;
}
#endif

#define SBAR() do { __builtin_amdgcn_sched_barrier(0); \
                    __builtin_amdgcn_s_barrier();      \
                    __builtin_amdgcn_sched_barrier(0); } while (0)

// ---- one-launch prep: all fp32->bf16 converts + RoPE cos/sin table ----
#define PB_X   8192
#define PB_WQ  (PB_X + 4096)
#define PB_WK  (PB_WQ + 1024)
#define PB_WV  (PB_WK + 1024)
#define PB_WO  (PB_WV + 4096)
#define PB_CS  (PB_WO + 512)
__global__ void k_prep(const float* __restrict__ x,
                       const float* __restrict__ Wq, const float* __restrict__ Wk,
                       const float* __restrict__ Wv, const float* __restrict__ Wo,
                       u16* __restrict__ xb, u16* __restrict__ Wqkvb,
                       u16* __restrict__ Wob, float* __restrict__ cs)
{
  const int bid = blockIdx.x, tid = threadIdx.x;
  const float* src; u16* dst; int i;
  if (bid < PB_X)       { i = bid * 256 + tid;            src = x;  dst = xb; }
  else if (bid < PB_WQ) { i = (bid - PB_X) * 256 + tid;   src = Wq; dst = Wqkvb; }
  else if (bid < PB_WK) { i = (bid - PB_WQ) * 256 + tid;  src = Wk; dst = Wqkvb + (size_t)2048 * HID; }
  else if (bid < PB_WV) { i = (bid - PB_WK) * 256 + tid;  src = Wv; dst = Wqkvb + (size_t)2560 * HID; }
  else if (bid < PB_WO) { i = (bid - PB_WV) * 256 + tid;  src = Wo; dst = Wob; }
  else {
    const int p = (bid - PB_WO) * 256 + tid;
    const int s = p >> 6, j = p & 63;
    float inv = expf(-(float)j * 0.14391156831212787f);
    float ang = (float)s * inv;
    float c, sn; sincosf(ang, &sn, &c);
    cs[p * 2 + 0] = c; cs[p * 2 + 1] = sn;
    return;
  }
  float4 v = ((const float4*)src)[i];
  ushort4 o;
  o.x = f2b(v.x); o.y = f2b(v.y); o.z = f2b(v.z); o.w = f2b(v.w);
  ((ushort4*)dst)[i] = o;
}

// ======================================================================
// 8-phase-style 256x256 GEMM (QKV): T2 swizzle + T3/T4 counted vmcnt + T5
// ======================================================================
#define MFMA_GRP(AV, BV, MO, NO)                                              \
  __builtin_amdgcn_s_setprio(1);                                              \
  _Pragma("unroll") for (int kk = 0; kk < 2; ++kk)                            \
  _Pragma("unroll") for (int mm = 0; mm < 4; ++mm)                            \
  _Pragma("unroll") for (int nn = 0; nn < 2; ++nn)                            \
    acc[(MO) + mm][(NO) + nn] = __builtin_amdgcn_mfma_f32_16x16x32_bf16(      \
        AV[kk][mm], BV[kk][nn], acc[(MO) + mm][(NO) + nn], 0, 0, 0);          \
  __builtin_amdgcn_s_setprio(0);

template <int OUT_BF16>
__global__ __launch_bounds__(512, 2) void k_gemm256(
    const u16* __restrict__ A, const u16* __restrict__ Bm, void* __restrict__ Cv,
    int M, int N, int K)
{
  __shared__ u16 AL[2][2][8192];   // 64 KB
  __shared__ u16 BL[2][2][8192];   // 64 KB
  const int tid = threadIdx.x;
  const int wave = tid >> 6, lane = tid & 63;
  const int l15 = lane & 15, l4 = lane >> 4;
  const int wr = wave >> 2, wc = wave & 3;
  const int gx = gridDim.x;
  const int nwg = gx * gridDim.y;
  int bid = blockIdx.y * gx + blockIdx.x;
  bid = (bid & 7) * (nwg >> 3) + (bid >> 3);
  const int col0 = (bid % gx) * 256, row0 = (bid / gx) * 256;

  int srcOff[2], dstD[2];
#pragma unroll
  for (int li = 0; li < 2; ++li) {
    const int D = (li * 512 + tid) * 16;
    const int off_p = D & 1023, si = D >> 10;
    const int off_l = off_p ^ (((off_p >> 9) & 1) << 5);
    const int R = si >> 1, C = si & 1;
    const int row = R * 16 + (off_l >> 6);
    const int colb = C * 64 + (off_l & 63);
    srcOff[li] = row * K + (colb >> 1);
    dstD[li] = D;
  }
  const int laneoff = (l15 * 64 + l4 * 16) ^ ((l15 >> 3) << 5);

  auto stage = [&](const u16* __restrict__ G, int grow0, int kb, u16* lds) {
#pragma unroll
    for (int li = 0; li < 2; ++li)
      gload_lds16(G + (size_t)grow0 * K + kb + srcOff[li],
                  (u16*)((char*)lds + dstD[li]));
  };

  f32x4 acc[8][4];
#pragma unroll
  for (int m = 0; m < 8; ++m)
#pragma unroll
    for (int n = 0; n < 4; ++n) acc[m][n] = f32x4{0.f, 0.f, 0.f, 0.f};

  const int nk = K >> 6;
  stage(A,  row0,       0,  &AL[0][0][0]);
  stage(A,  row0 + 128, 0,  &AL[0][1][0]);
  stage(Bm, col0,       0,  &BL[0][0][0]);
  stage(Bm, col0 + 128, 0,  &BL[0][1][0]);
  stage(A,  row0,       64, &AL[1][0][0]);
  stage(A,  row0 + 128, 64, &AL[1][1][0]);
  asm volatile("s_waitcnt vmcnt(4)" ::: "memory");
  SBAR();

  for (int t = 0; t < nk; ++t) {
    const int bi = t & 1;
    const bool sB = (t + 1 < nk);
    const bool sA = (t + 2 < nk);
    const char* Ab = (const char*)&AL[bi][wr][0];
    const char* Bb = (const char*)&BL[bi][wc >> 1][0] + (wc & 1) * 8192;
    bf16x8 a0[2][4], a1[2][4], b0[2][2], b1[2][2];
#pragma unroll
    for (int kk = 0; kk < 2; ++kk)
#pragma unroll
      for (int m = 0; m < 4; ++m)
        a0[kk][m] = *(const bf16x8*)(Ab + m * 2048 + kk * 1024 + laneoff);
#pragma unroll
    for (int kk = 0; kk < 2; ++kk)
#pragma unroll
      for (int n = 0; n < 2; ++n)
        b0[kk][n] = *(const bf16x8*)(Bb + n * 2048 + kk * 1024 + laneoff);
    if (sB) stage(Bm, col0, (t + 1) * 64, &BL[bi ^ 1][0][0]);
    SBAR();
    MFMA_GRP(a0, b0, 0, 0);
    SBAR();
#pragma unroll
    for (int kk = 0; kk < 2; ++kk)
#pragma unroll
      for (int m = 0; m < 4; ++m)
        a1[kk][m] = *(const bf16x8*)(Ab + (m + 4) * 2048 + kk * 1024 + laneoff);
    if (sB) stage(Bm, col0 + 128, (t + 1) * 64, &BL[bi ^ 1][1][0]);
    SBAR();
    MFMA_GRP(a1, b0, 4, 0);
    SBAR();
#pragma unroll
    for (int kk = 0; kk < 2; ++kk)
#pragma unroll
      for (int n = 0; n < 2; ++n)
        b1[kk][n] = *(const bf16x8*)(Bb + (n + 2) * 2048 + kk * 1024 + laneoff);
    if (sA) stage(A, row0, (t + 2) * 64, &AL[bi][0][0]);
    SBAR();
    MFMA_GRP(a1, b1, 4, 2);
    SBAR();
    if (sA) {
      stage(A, row0 + 128, (t + 2) * 64, &AL[bi][1][0]);
      asm volatile("s_waitcnt vmcnt(4)" ::: "memory");
    } else if (sB) {
      asm volatile("s_waitcnt vmcnt(0)" ::: "memory");
    }
    SBAR();
    MFMA_GRP(a0, b1, 0, 2);
    SBAR();
  }

#pragma unroll
  for (int m = 0; m < 8; ++m) {
    const int r = row0 + wr * 128 + m * 16 + l4 * 4;
#pragma unroll
    for (int n = 0; n < 4; ++n) {
      const int c = col0 + wc * 64 + n * 16 + l15;
#pragma unroll
      for (int j = 0; j < 4; ++j) {
        const float v = acc[m][n][j];
        if (OUT_BF16) ((u16*)Cv)[(size_t)(r + j) * N + c] = f2b(v);
        else          ((float*)Cv)[(size_t)(r + j) * N + c] = v;
      }
    }
  }
}

// ======================================================================
// 256x128-tile 8-phase GEMM (out-proj): grid 16x16 = 256 blocks = 1/CU.
// 8 waves = 4M x 2N, per-wave 64x64, acc 4x4. LDS 96 KB (A 64 + B 32).
// Stage schedule per tile t: B(t+1)@P1, A-h0(t+2)@P3, A-h1(t+2)@P4;
// vmcnt(4) at P4 leaves exactly A(t+2) in flight (B(t+1)+A(t+1) landed).
// ======================================================================
#define MFMA_GRP2(AV, BV, MO, NO)                                             \
  __builtin_amdgcn_s_setprio(1);                                              \
  _Pragma("unroll") for (int kk = 0; kk < 2; ++kk)                            \
  _Pragma("unroll") for (int mm = 0; mm < 2; ++mm)                            \
  _Pragma("unroll") for (int nn = 0; nn < 2; ++nn)                            \
    acc[(MO) + mm][(NO) + nn] = __builtin_amdgcn_mfma_f32_16x16x32_bf16(      \
        AV[kk][mm], BV[kk][nn], acc[(MO) + mm][(NO) + nn], 0, 0, 0);          \
  __builtin_amdgcn_s_setprio(0);

__global__ __launch_bounds__(512, 1) void k_gemm_op(
    const u16* __restrict__ A, const u16* __restrict__ Bm,
    float* __restrict__ C, int M, int N, int K)
{
  __shared__ u16 AL[2][2][8192];   // 64 KB: 2 x (128 rows x 64 k)
  __shared__ u16 BL[2][8192];      // 32 KB: 128 rows x 64 k
  const int tid = threadIdx.x;
  const int wave = tid >> 6, lane = tid & 63;
  const int l15 = lane & 15, l4 = lane >> 4;
  const int wr = wave >> 1, wc = wave & 1;   // 4 M-groups x 2 N-groups
  const int gx = gridDim.x;                  // N/128 = 16
  const int nwg = gx * gridDim.y;            // 256
  int bid = blockIdx.y * gx + blockIdx.x;
  bid = (bid & 7) * (nwg >> 3) + (bid >> 3);
  const int col0 = (bid % gx) * 128, row0 = (bid / gx) * 256;

  int srcOff[2], dstD[2];
#pragma unroll
  for (int li = 0; li < 2; ++li) {
    const int D = (li * 512 + tid) * 16;
    const int off_p = D & 1023, si = D >> 10;
    const int off_l = off_p ^ (((off_p >> 9) & 1) << 5);
    const int R = si >> 1, Cc = si & 1;
    const int row = R * 16 + (off_l >> 6);
    const int colb = Cc * 64 + (off_l & 63);
    srcOff[li] = row * K + (colb >> 1);
    dstD[li] = D;
  }
  const int laneoff = (l15 * 64 + l4 * 16) ^ ((l15 >> 3) << 5);

  auto stage = [&](const u16* __restrict__ G, int grow0, int kb, u16* lds) {
#pragma unroll
    for (int li = 0; li < 2; ++li)
      gload_lds16(G + (size_t)grow0 * K + kb + srcOff[li],
                  (u16*)((char*)lds + dstD[li]));
  };

  f32x4 acc[4][4];
#pragma unroll
  for (int m = 0; m < 4; ++m)
#pragma unroll
    for (int n = 0; n < 4; ++n) acc[m][n] = f32x4{0.f, 0.f, 0.f, 0.f};

  const int nk = K >> 6;
  // prologue: tile0 (A both halves + B) then tile1 A halves; B(1) staged in iter0
  stage(A,  row0,       0,  &AL[0][0][0]);
  stage(A,  row0 + 128, 0,  &AL[0][1][0]);
  stage(Bm, col0,       0,  &BL[0][0]);
  stage(A,  row0,       64, &AL[1][0][0]);
  stage(A,  row0 + 128, 64, &AL[1][1][0]);
  asm volatile("s_waitcnt vmcnt(4)" ::: "memory");   // tile0 landed
  SBAR();

  for (int t = 0; t < nk; ++t) {
    const int bi = t & 1;
    const bool sB = (t + 1 < nk);
    const bool sA = (t + 2 < nk);
    const char* Ab = (const char*)&AL[bi][wr >> 1][0];
    const int am = (wr & 1) * 4;     // row-block base within A half
    const char* Bb = (const char*)&BL[bi][0];
    const int bn = wc * 4;           // row-block base within B tile
    bf16x8 a0[2][2], a1[2][2], b0[2][2], b1[2][2];
    // ---- P1: read a(m0,m1) + b(n0,n1); stage B(t+1) ----
#pragma unroll
    for (int kk = 0; kk < 2; ++kk)
#pragma unroll
      for (int m = 0; m < 2; ++m)
        a0[kk][m] = *(const bf16x8*)(Ab + (am + m) * 2048 + kk * 1024 + laneoff);
#pragma unroll
    for (int kk = 0; kk < 2; ++kk)
#pragma unroll
      for (int n = 0; n < 2; ++n)
        b0[kk][n] = *(const bf16x8*)(Bb + (bn + n) * 2048 + kk * 1024 + laneoff);
    if (sB) stage(Bm, col0, (t + 1) * 64, &BL[bi ^ 1][0]);
    SBAR();
    MFMA_GRP2(a0, b0, 0, 0);
    SBAR();
    // ---- P2: read a(m2,m3) ----
#pragma unroll
    for (int kk = 0; kk < 2; ++kk)
#pragma unroll
      for (int m = 0; m < 2; ++m)
        a1[kk][m] = *(const bf16x8*)(Ab + (am + 2 + m) * 2048 + kk * 1024 + laneoff);
    SBAR();
    MFMA_GRP2(a1, b0, 2, 0);
    SBAR();
    // ---- P3: read b(n2,n3); stage A-h0(t+2) (all A reads done by P2 barrier) ----
#pragma unroll
    for (int kk = 0; kk < 2; ++kk)
#pragma unroll
      for (int n = 0; n < 2; ++n)
        b1[kk][n] = *(const bf16x8*)(Bb + (bn + 2 + n) * 2048 + kk * 1024 + laneoff);
    if (sA) stage(A, row0, (t + 2) * 64, &AL[bi][0][0]);
    SBAR();
    MFMA_GRP2(a1, b1, 2, 2);
    SBAR();
    // ---- P4: stage A-h1(t+2); counted vmcnt ----
    if (sA) {
      stage(A, row0 + 128, (t + 2) * 64, &AL[bi][1][0]);
      asm volatile("s_waitcnt vmcnt(4)" ::: "memory");   // B(t+1)+A(t+1) landed
    } else if (sB) {
      asm volatile("s_waitcnt vmcnt(0)" ::: "memory");   // tail drain
    }
    SBAR();
    MFMA_GRP2(a0, b1, 0, 2);
    SBAR();
  }

  // ---- epilogue (fp32 out) ----
#pragma unroll
  for (int m = 0; m < 4; ++m) {
    const int r = row0 + wr * 64 + m * 16 + l4 * 4;
#pragma unroll
    for (int n = 0; n < 4; ++n) {
      const int c = col0 + wc * 64 + n * 16 + l15;
#pragma unroll
      for (int j = 0; j < 4; ++j)
        C[(size_t)(r + j) * N + c] = acc[m][n][j];
    }
  }
}

// ---- fused RoPE (Q pre-scaled by scale*log2e) + K RoPE + V transpose ----
__global__ __launch_bounds__(256) void k_ropev(
    const u16* __restrict__ qkv, const float* __restrict__ cs,
    u16* __restrict__ Qr, u16* __restrict__ Kr, u16* __restrict__ Vt)
{
  const int blk = blockIdx.x;            // b*256 + (s>>3)
  const int b = blk >> 8, s0 = (blk & 255) << 3;
  const int tid = threadIdx.x;
  const float S2 = 0.08838834764831845f * 1.4426950408889634f;
#pragma unroll
  for (int p = tid; p < 1024; p += 256) {
    const int s = p >> 7, rem = p & 127, h = rem >> 3, j8 = (rem & 7) * 8;
    const int sg = s0 + s;
    const u16* src = qkv + (size_t)(b * S_LEN + sg) * QKV_N + h * 128 + j8;
    union { uint4 v; u16 u[8]; } lo, hi, olo, ohi;
    lo.v = *(const uint4*)(src);
    hi.v = *(const uint4*)(src + 64);
    const float* cp = cs + (size_t)(sg * 64 + j8) * 2;
#pragma unroll
    for (int k = 0; k < 8; ++k) {
      const float c = cp[k * 2], sn = cp[k * 2 + 1];
      const float x0 = b2f(lo.u[k]), x1 = b2f(hi.u[k]);
      olo.u[k] = f2b((x0 * c - x1 * sn) * S2);
      ohi.u[k] = f2b((x1 * c + x0 * sn) * S2);
    }
    u16* dst = Qr + ((size_t)(b * NHEADS + h) * S_LEN + sg) * HDIM + j8;
    *(uint4*)(dst) = olo.v;
    *(uint4*)(dst + 64) = ohi.v;
  }
  {
    const int p = tid;
    const int s = p >> 5, rem = p & 31, h = rem >> 3, j8 = (rem & 7) * 8;
    const int sg = s0 + s;
    const u16* src = qkv + (size_t)(b * S_LEN + sg) * QKV_N + 2048 + h * 128 + j8;
    union { uint4 v; u16 u[8]; } lo, hi, olo, ohi;
    lo.v = *(const uint4*)(src);
    hi.v = *(const uint4*)(src + 64);
    const float* cp = cs + (size_t)(sg * 64 + j8) * 2;
#pragma unroll
    for (int k = 0; k < 8; ++k) {
      const float c = cp[k * 2], sn = cp[k * 2 + 1];
      const float x0 = b2f(lo.u[k]), x1 = b2f(hi.u[k]);
      olo.u[k] = f2b(x0 * c - x1 * sn);
      ohi.u[k] = f2b(x1 * c + x0 * sn);
    }
    u16* dst = Kr + ((size_t)(b * NKVH + h) * S_LEN + sg) * HDIM + j8;
    *(uint4*)(dst) = olo.v;
    *(uint4*)(dst + 64) = ohi.v;
  }
#pragma unroll
  for (int vi = 0; vi < 2; ++vi) {
    const int idx = vi * 256 + tid, h = idx >> 7, d = idx & 127;
    union { u16 u[8]; uint4 v; } bb;
#pragma unroll
    for (int s = 0; s < 8; ++s)
      bb.u[s] = qkv[(size_t)(b * S_LEN + s0 + s) * QKV_N + 2560 + idx];
    *(uint4*)(Vt + ((size_t)(b * NKVH + h) * HDIM + d) * S_LEN + s0) = bb.v;
  }
}

// ---- flash attention v15 (best measured 78.4 us): v6 per-wave body;
// ---- 512-thr block = 2 heads sharing one KV LDS stream ----
__device__ __forceinline__ void attn_qtile(
    int qt, int lastPhase,
    const u16* __restrict__ Q, const u16* __restrict__ Kg, const u16* __restrict__ Vg,
    u16* __restrict__ Out, int bh,
    u16* Kl0, u16* Kl1, u16* Vl0, u16* Vl1,
    const int (&ko)[2], const int (&vo)[2],
    int wave, int w4, int lane, int& cur)
{
  const int l15 = lane & 15, l4 = lane >> 4;
  const int b = bh >> 4, h = bh & 15;
  const int qw0 = qt * 64 + w4 * 16;
  const u16* Qg = Q + ((size_t)bh * S_LEN + qw0) * HDIM;

  bf16x8 qf[4];
#pragma unroll
  for (int kc = 0; kc < 4; ++kc)
    qf[kc] = *(const bf16x8*)(Qg + l15 * HDIM + kc * 32 + l4 * 8);

  f32x4 zero = {0.f, 0.f, 0.f, 0.f};
  f32x4 oacc[8];
#pragma unroll
  for (int i = 0; i < 8; ++i) oacc[i] = zero;
  float m_r = -1e30f, l_p = 0.f;

  const int nt = qt + 1;
  const int qg = qw0 + l15;

  for (int t = 0; t < nt; ++t) {
    const int kt = t * 64;
    u16* Vb = cur ? Vl1 : Vl0;
#pragma unroll
    for (int it = 0; it < 2; ++it)
      gload_lds16(Vg + (size_t)vo[it] + kt, Vb + (it * 8 + wave) * 512);
    const int hasNext = (t + 1 < nt) || (!lastPhase);
    const int ktn = (t + 1 < nt) ? kt + 64 : 0;
    u16* Kn = cur ? Kl0 : Kl1;
    if (hasNext) {
#pragma unroll
      for (int it = 0; it < 2; ++it)
        gload_lds16(Kg + (size_t)ktn * HDIM + ko[it], Kn + (it * 8 + wave) * 512);
      asm volatile("s_waitcnt vmcnt(4)" ::: "memory");
    } else {
      asm volatile("s_waitcnt vmcnt(2)" ::: "memory");
    }
    SBAR();

    const char* Kb = (const char*)(cur ? Kl1 : Kl0);
    f32x4 s[4];
#pragma unroll
    for (int n = 0; n < 4; ++n) s[n] = zero;
    __builtin_amdgcn_s_setprio(1);
#pragma unroll
    for (int n = 0; n < 4; ++n) {
      const int row = n * 16 + l15;
#pragma unroll
      for (int kc = 0; kc < 4; ++kc) {
        const int ab = (row * 256 + kc * 64 + l4 * 16) ^ ((row & 7) << 4);
        bf16x8 kf = *(const bf16x8*)(Kb + ab);
        s[n] = __builtin_amdgcn_mfma_f32_16x16x32_bf16(kf, qf[kc], s[n], 0, 0, 0);
      }
    }
    __builtin_amdgcn_s_setprio(0);
    float sv[4][4];
    if (kt + 63 > qw0) {
#pragma unroll
      for (int n = 0; n < 4; ++n)
#pragma unroll
        for (int j = 0; j < 4; ++j) {
          float x = s[n][j];
          if (kt + n * 16 + l4 * 4 + j > qg) x = -1e30f;
          sv[n][j] = x;
        }
    } else {
#pragma unroll
      for (int n = 0; n < 4; ++n)
#pragma unroll
        for (int j = 0; j < 4; ++j) sv[n][j] = s[n][j];
    }
    float pm = sv[0][0];
#pragma unroll
    for (int n = 0; n < 4; ++n)
#pragma unroll
      for (int j = 0; j < 4; ++j) pm = fmaxf(pm, sv[n][j]);
    if (!__all(pm <= m_r + 11.5416f)) {
      float pf = fmaxf(pm, __shfl_xor(pm, 16, 64));
      pf = fmaxf(pf, __shfl_xor(pf, 32, 64));
      const float mn = fmaxf(m_r, pf);
      const float sc = exp2f(m_r - mn);
      m_r = mn;
      l_p *= sc;
      float scq[4];
#pragma unroll
      for (int j = 0; j < 4; ++j) scq[j] = __shfl(sc, l4 * 4 + j, 64);
#pragma unroll
      for (int nd = 0; nd < 8; ++nd)
#pragma unroll
        for (int j = 0; j < 4; ++j) oacc[nd][j] *= scq[j];
    }
    union { unsigned u[2]; s16x4 v; } a[4];
#pragma unroll
    for (int n = 0; n < 4; ++n) {
      const float p0 = exp2f(sv[n][0] - m_r);
      const float p1 = exp2f(sv[n][1] - m_r);
      const float p2 = exp2f(sv[n][2] - m_r);
      const float p3 = exp2f(sv[n][3] - m_r);
      l_p += (p0 + p1) + (p2 + p3);
      a[n].u[0] = cvtpk(p0, p1);
      a[n].u[1] = cvtpk(p2, p3);
    }
    if (hasNext) asm volatile("s_waitcnt vmcnt(2)" ::: "memory");
    else         asm volatile("s_waitcnt vmcnt(0)" ::: "memory");
    SBAR();
    __builtin_amdgcn_s_setprio(1);
#pragma unroll
    for (int nd = 0; nd < 8; ++nd) {
      const int d = nd * 16 + l15;
      const int rowb = d * 128, swz = (d & 7) << 4;
#pragma unroll
      for (int n = 0; n < 4; ++n) {
        const int ab = (rowb + n * 32 + l4 * 8) ^ swz;
        s16x4 vf = *(const s16x4*)((const char*)Vb + ab);
        oacc[nd] = mfma16(a[n].v, vf, oacc[nd]);
      }
    }
    __builtin_amdgcn_s_setprio(0);
    cur ^= 1;
  }

  l_p += __shfl_xor(l_p, 16, 64);
  l_p += __shfl_xor(l_p, 32, 64);
  float il[4];
#pragma unroll
  for (int j = 0; j < 4; ++j) il[j] = 1.f / __shfl(l_p, l4 * 4 + j, 64);
  const size_t obase = ((size_t)b * S_LEN + qw0 + l4 * 4) * HID + h * HDIM;
#pragma unroll
  for (int nd = 0; nd < 8; ++nd)
#pragma unroll
    for (int j = 0; j < 4; ++j)
      Out[obase + (size_t)j * HID + nd * 16 + l15] = f2b(oacc[nd][j] * il[j]);
}

__global__ __launch_bounds__(512) void k_attn(
    const u16* __restrict__ Q, const u16* __restrict__ Kr,
    const u16* __restrict__ Vt, u16* __restrict__ Out)
{
  __shared__ u16 Kl[2][64 * 128];   // 32 KB dbuf, XOR ^((kv&7)<<4)
  __shared__ u16 Vl[2][128 * 64];   // 32 KB dbuf, XOR ^((d&7)<<4)
  const int tid = threadIdx.x;
  const int wave = tid >> 6, lane = tid & 63;
  const int bx = blockIdx.x;              // hp*8 + b*4 + kvh : XCD = bx%8
  const int pairi = blockIdx.y;           // pair (31-pairi, pairi)
  const int kvh = bx & 3, b = (bx >> 2) & 1, hp = bx >> 3;
  const int h = kvh * 4 + hp + (wave >> 2) * 2;   // waves 0-3: h, 4-7: h+2
  const int bh = b * NHEADS + h;
  const int w4 = wave & 3;

  const u16* Kg = Kr + (size_t)(b * NKVH + kvh) * S_LEN * HDIM;
  const u16* Vg = Vt + (size_t)(b * NKVH + kvh) * HDIM * S_LEN;

  int ko[2], vo[2];
#pragma unroll
  for (int it = 0; it < 2; ++it) {
    const int c = it * 8 + wave;
    const int L = c * 1024 + lane * 16;
    const int r = L >> 8;  const int w2 = (L & 255) ^ ((r & 7) << 4);
    ko[it] = r * HDIM + (w2 >> 1);
    const int d = L >> 7;  const int wv = (L & 127) ^ ((d & 7) << 4);
    vo[it] = d * S_LEN + (wv >> 1);
  }
#pragma unroll
  for (int it = 0; it < 2; ++it)
    gload_lds16(Kg + ko[it], &Kl[0][(it * 8 + wave) * 512]);

  int cur = 0;
  attn_qtile(31 - pairi, 0, Q, Kg, Vg, Out, bh, &Kl[0][0], &Kl[1][0],
             &Vl[0][0], &Vl[1][0], ko, vo, wave, w4, lane, cur);
  attn_qtile(pairi,      1, Q, Kg, Vg, Out, bh, &Kl[0][0], &Kl[1][0],
             &Vl[0][0], &Vl[1][0], ko, vo, wave, w4, lane, cur);
}

extern "C" void kernel_launch(void* const* d_in, const int* in_sizes, int n_in,
                              void* d_out, int out_size, void* d_ws, size_t ws_size,
                              hipStream_t stream)
{
  const float* x  = (const float*)d_in[0];
  const float* Wq = (const float*)d_in[2];
  const float* Wk = (const float*)d_in[3];
  const float* Wv = (const float*)d_in[4];
  const float* Wo = (const float*)d_in[5];
  float* out = (float*)d_out;

  u16* xb    = (u16*)d_ws;
  u16* Wqkvb = xb    + (size_t)MROWS * HID;
  u16* Wob   = Wqkvb + (size_t)QKV_N * HID;
  u16* qkv   = Wob   + (size_t)HID * HID;
  u16* Qr    = qkv   + (size_t)MROWS * QKV_N;
  u16* Kr    = Qr    + (size_t)BB * NHEADS * S_LEN * HDIM;
  u16* Vt    = Kr    + (size_t)BB * NKVH * S_LEN * HDIM;
  u16* attn  = Vt    + (size_t)BB * NKVH * S_LEN * HDIM;
  float* cs  = (float*)(attn + (size_t)MROWS * HID);

  k_prep<<<dim3(PB_CS), 256, 0, stream>>>(x, Wq, Wk, Wv, Wo, xb, Wqkvb, Wob, cs);
  k_gemm256<1><<<dim3(QKV_N / 256, MROWS / 256), 512, 0, stream>>>(xb, Wqkvb, qkv, MROWS, QKV_N, HID);
  k_ropev<<<dim3(BB * 256), 256, 0, stream>>>(qkv, cs, Qr, Kr, Vt);
  k_attn<<<dim3(16, 16), 512, 0, stream>>>(Qr, Kr, Vt, attn);
  k_gemm_op<<<dim3(HID / 128, MROWS / 256), 512, 0, stream>>>(attn, Wob, out, MROWS, HID, HID);
}

// Round 19
// 199.719 us; speedup vs baseline: 1.0538x; 1.0333x over previous
//
#include <hip/hip_runtime.h>

typedef unsigned short u16;
typedef __bf16 bf16x8 __attribute__((ext_vector_type(8)));
typedef float f32x4 __attribute__((ext_vector_type(4)));
typedef short s16x4 __attribute__((ext_vector_type(4)));

#define S_LEN  2048
#define NHEADS 16
#define NKVH   4
#define HDIM   128
#define BB     2
#define MROWS  4096   // B*S
#define QKV_N  3072   // NH*HD + 2*NKV*HD
#define HID    2048

__device__ __forceinline__ u16 f2b(float f) {
  union { float f; unsigned u; } x; x.f = f;
  unsigned r = x.u + 0x7fffu + ((x.u >> 16) & 1u);
  return (u16)(r >> 16);
}
__device__ __forceinline__ float b2f(u16 v) {
  union { unsigned u; float f; } x; x.u = ((unsigned)v) << 16;
  return x.f;
}
__device__ __forceinline__ void gload_lds16(const u16* g, u16* l) {
  __builtin_amdgcn_global_load_lds((__attribute__((address_space(1))) void*)g,
                                   (__attribute__((address_space(3))) void*)l,
                                   16, 0, 0);
}
__device__ __forceinline__ unsigned cvtpk(float lo, float hi) {
  unsigned r;
  asm("v_cvt_pk_bf16_f32 %0, %1, %2" : "=v"(r) : "v"(lo), "v"(hi));
  return r;
}
#if __has_builtin(__builtin_amdgcn_mfma_f32_16x16x16bf16_1k)
__device__ __forceinline__ f32x4 mfma16(s16x4 a, s16x4 b, f32x4 c) {
  return __builtin_amdgcn_mfma_f32_16x16x16bf16_1k(a, b, c, 0, 0, 0);
}
#else
__device__ __forceinline__ f32x4 mfma16(s16x4 a, s16x4 b, f32x4 c) {
  asm("v_mfma_f32_16x16x16_bf16 %0, %1, %2, %0" : "+v"(c) : "v"(a), "v"(b));
  return c;
}
#endif

#define SBAR() do { __builtin_amdgcn_sched_barrier(0); \
                    __builtin_amdgcn_s_barrier();      \
                    __builtin_amdgcn_sched_barrier(0); } while (0)

// ---- one-launch prep: all fp32->bf16 converts + RoPE cos/sin table ----
#define PB_X   8192
#define PB_WQ  (PB_X + 4096)
#define PB_WK  (PB_WQ + 1024)
#define PB_WV  (PB_WK + 1024)
#define PB_WO  (PB_WV + 4096)
#define PB_CS  (PB_WO + 512)
__global__ void k_prep(const float* __restrict__ x,
                       const float* __restrict__ Wq, const float* __restrict__ Wk,
                       const float* __restrict__ Wv, const float* __restrict__ Wo,
                       u16* __restrict__ xb, u16* __restrict__ Wqkvb,
                       u16* __restrict__ Wob, float* __restrict__ cs)
{
  const int bid = blockIdx.x, tid = threadIdx.x;
  const float* src; u16* dst; int i;
  if (bid < PB_X)       { i = bid * 256 + tid;            src = x;  dst = xb; }
  else if (bid < PB_WQ) { i = (bid - PB_X) * 256 + tid;   src = Wq; dst = Wqkvb; }
  else if (bid < PB_WK) { i = (bid - PB_WQ) * 256 + tid;  src = Wk; dst = Wqkvb + (size_t)2048 * HID; }
  else if (bid < PB_WV) { i = (bid - PB_WK) * 256 + tid;  src = Wv; dst = Wqkvb + (size_t)2560 * HID; }
  else if (bid < PB_WO) { i = (bid - PB_WV) * 256 + tid;  src = Wo; dst = Wob; }
  else {
    const int p = (bid - PB_WO) * 256 + tid;
    const int s = p >> 6, j = p & 63;
    float inv = expf(-(float)j * 0.14391156831212787f);
    float ang = (float)s * inv;
    float c, sn; sincosf(ang, &sn, &c);
    cs[p * 2 + 0] = c; cs[p * 2 + 1] = sn;
    return;
  }
  float4 v = ((const float4*)src)[i];
  ushort4 o;
  o.x = f2b(v.x); o.y = f2b(v.y); o.z = f2b(v.z); o.w = f2b(v.w);
  ((ushort4*)dst)[i] = o;
}

// ======================================================================
// 256x192-tile 8-phase GEMM (QKV): grid 16x16 = 256 blocks = 1/CU.
// 8 waves = 2M x 4N (per-wave 128x48, acc[8][3]). BK=64.
// LDS 112 KB: A 2buf x 2half x 16KB + B 2buf x 24KB. st_16x32 swizzle.
// Stage per tile t: B(t+1)@P1 (3 loads), A-h0(t+2)@P3, A-h1(t+2)@P4;
// vmcnt(4)@P4 leaves exactly A(t+2) in flight.
// ======================================================================
#define MFMA_G3(AV, NLO, NHI, MO)                                             \
  __builtin_amdgcn_s_setprio(1);                                              \
  _Pragma("unroll") for (int kk = 0; kk < 2; ++kk)                            \
  _Pragma("unroll") for (int mm = 0; mm < 4; ++mm)                            \
  _Pragma("unroll") for (int nn = (NLO); nn <= (NHI); ++nn)                   \
    acc[(MO) + mm][nn] = __builtin_amdgcn_mfma_f32_16x16x32_bf16(             \
        AV[kk][mm], bfr[kk][nn], acc[(MO) + mm][nn], 0, 0, 0);                \
  __builtin_amdgcn_s_setprio(0);

__global__ __launch_bounds__(512, 1) void k_gemm_qkv(
    const u16* __restrict__ A, const u16* __restrict__ Bm,
    u16* __restrict__ C, int M, int N, int K)
{
  __shared__ u16 AL[2][2][8192];   // 64 KB: [buf][128-row half][64 k]
  __shared__ u16 BL[2][12288];     // 48 KB: [buf][192 rows x 64 k]
  const int tid = threadIdx.x;
  const int wave = tid >> 6, lane = tid & 63;
  const int l15 = lane & 15, l4 = lane >> 4;
  const int wr = wave >> 2, wc = wave & 3;   // 2 M x 4 N
  const int gx = gridDim.x;                  // 16 = N/192
  const int nwg = gx * gridDim.y;            // 256
  int bid = blockIdx.y * gx + blockIdx.x;
  bid = (bid & 7) * (nwg >> 3) + (bid >> 3);
  const int col0 = (bid % gx) * 192, row0 = (bid / gx) * 256;

  // staging offsets (rule 21 + st_16x32): A half = 16 KB (2 loads),
  // B tile = 24 KB (3 loads); same subtile decode, D range extended.
  int soA[2], dA[2], soB[3], dB[3];
#pragma unroll
  for (int li = 0; li < 3; ++li) {
    const int D = (li * 512 + tid) * 16;
    const int off_p = D & 1023, si = D >> 10;
    const int off_l = off_p ^ (((off_p >> 9) & 1) << 5);
    const int R = si >> 1, Cc = si & 1;
    const int row = R * 16 + (off_l >> 6);
    const int colb = Cc * 64 + (off_l & 63);
    const int so = row * K + (colb >> 1);
    if (li < 2) { soA[li] = so; dA[li] = D; }
    soB[li] = so; dB[li] = D;
  }
  const int laneoff = (l15 * 64 + l4 * 16) ^ ((l15 >> 3) << 5);

  auto stageA = [&](int grow0, int kb, u16* lds) {
#pragma unroll
    for (int li = 0; li < 2; ++li)
      gload_lds16(A + (size_t)grow0 * K + kb + soA[li],
                  (u16*)((char*)lds + dA[li]));
  };
  auto stageB = [&](int kb, u16* lds) {
#pragma unroll
    for (int li = 0; li < 3; ++li)
      gload_lds16(Bm + (size_t)col0 * K + kb + soB[li],
                  (u16*)((char*)lds + dB[li]));
  };

  f32x4 acc[8][3];
#pragma unroll
  for (int m = 0; m < 8; ++m)
#pragma unroll
    for (int n = 0; n < 3; ++n) acc[m][n] = f32x4{0.f, 0.f, 0.f, 0.f};

  const int nk = K >> 6;
  // prologue: tile0 (A h0,h1 + B) then tile1 A halves
  stageA(row0,       0,  &AL[0][0][0]);
  stageA(row0 + 128, 0,  &AL[0][1][0]);
  stageB(0, &BL[0][0]);
  stageA(row0,       64, &AL[1][0][0]);
  stageA(row0 + 128, 64, &AL[1][1][0]);
  asm volatile("s_waitcnt vmcnt(4)" ::: "memory");   // tile0 landed
  SBAR();

  for (int t = 0; t < nk; ++t) {
    const int bi = t & 1;
    const bool sB = (t + 1 < nk);
    const bool sA = (t + 2 < nk);
    const char* Ab = (const char*)&AL[bi][wr][0];
    const char* Bb = (const char*)&BL[bi][0] + wc * 6144;
    bf16x8 a0[2][4], a1[2][4], bfr[2][3];
    // ---- P1: read a(m0-3) + all b; stage B(t+1) ----
#pragma unroll
    for (int kk = 0; kk < 2; ++kk)
#pragma unroll
      for (int m = 0; m < 4; ++m)
        a0[kk][m] = *(const bf16x8*)(Ab + m * 2048 + kk * 1024 + laneoff);
#pragma unroll
    for (int kk = 0; kk < 2; ++kk)
#pragma unroll
      for (int n = 0; n < 3; ++n)
        bfr[kk][n] = *(const bf16x8*)(Bb + n * 2048 + kk * 1024 + laneoff);
    if (sB) stageB((t + 1) * 64, &BL[bi ^ 1][0]);
    SBAR();
    MFMA_G3(a0, 0, 1, 0);
    SBAR();
    // ---- P2: read a(m4-7) ----
#pragma unroll
    for (int kk = 0; kk < 2; ++kk)
#pragma unroll
      for (int m = 0; m < 4; ++m)
        a1[kk][m] = *(const bf16x8*)(Ab + (m + 4) * 2048 + kk * 1024 + laneoff);
    SBAR();
    MFMA_G3(a1, 0, 1, 4);
    SBAR();
    // ---- P3: stage A-h0(t+2) (A(t) reads all completed by P2 barrier) ----
    if (sA) stageA(row0, (t + 2) * 64, &AL[bi][0][0]);
    SBAR();
    MFMA_G3(a1, 2, 2, 4);
    SBAR();
    // ---- P4: stage A-h1(t+2); counted vmcnt ----
    if (sA) {
      stageA(row0 + 128, (t + 2) * 64, &AL[bi][1][0]);
      asm volatile("s_waitcnt vmcnt(4)" ::: "memory");   // A(t+1)+B(t+1) landed
    } else if (sB) {
      asm volatile("s_waitcnt vmcnt(0)" ::: "memory");
    }
    SBAR();
    MFMA_G3(a0, 2, 2, 0);
    SBAR();
  }

  // ---- epilogue (bf16 out) ----
#pragma unroll
  for (int m = 0; m < 8; ++m) {
    const int r = row0 + wr * 128 + m * 16 + l4 * 4;
#pragma unroll
    for (int n = 0; n < 3; ++n) {
      const int c = col0 + wc * 48 + n * 16 + l15;
#pragma unroll
      for (int j = 0; j < 4; ++j)
        C[(size_t)(r + j) * N + c] = f2b(acc[m][n][j]);
    }
  }
}

// ======================================================================
// 256x128-tile 8-phase GEMM (out-proj): grid 16x16 = 256 blocks = 1/CU.
// ======================================================================
#define MFMA_GRP2(AV, BV, MO, NO)                                             \
  __builtin_amdgcn_s_setprio(1);                                              \
  _Pragma("unroll") for (int kk = 0; kk < 2; ++kk)                            \
  _Pragma("unroll") for (int mm = 0; mm < 2; ++mm)                            \
  _Pragma("unroll") for (int nn = 0; nn < 2; ++nn)                            \
    acc[(MO) + mm][(NO) + nn] = __builtin_amdgcn_mfma_f32_16x16x32_bf16(      \
        AV[kk][mm], BV[kk][nn], acc[(MO) + mm][(NO) + nn], 0, 0, 0);          \
  __builtin_amdgcn_s_setprio(0);

__global__ __launch_bounds__(512, 1) void k_gemm_op(
    const u16* __restrict__ A, const u16* __restrict__ Bm,
    float* __restrict__ C, int M, int N, int K)
{
  __shared__ u16 AL[2][2][8192];   // 64 KB
  __shared__ u16 BL[2][8192];      // 32 KB
  const int tid = threadIdx.x;
  const int wave = tid >> 6, lane = tid & 63;
  const int l15 = lane & 15, l4 = lane >> 4;
  const int wr = wave >> 1, wc = wave & 1;
  const int gx = gridDim.x;
  const int nwg = gx * gridDim.y;
  int bid = blockIdx.y * gx + blockIdx.x;
  bid = (bid & 7) * (nwg >> 3) + (bid >> 3);
  const int col0 = (bid % gx) * 128, row0 = (bid / gx) * 256;

  int srcOff[2], dstD[2];
#pragma unroll
  for (int li = 0; li < 2; ++li) {
    const int D = (li * 512 + tid) * 16;
    const int off_p = D & 1023, si = D >> 10;
    const int off_l = off_p ^ (((off_p >> 9) & 1) << 5);
    const int R = si >> 1, Cc = si & 1;
    const int row = R * 16 + (off_l >> 6);
    const int colb = Cc * 64 + (off_l & 63);
    srcOff[li] = row * K + (colb >> 1);
    dstD[li] = D;
  }
  const int laneoff = (l15 * 64 + l4 * 16) ^ ((l15 >> 3) << 5);

  auto stage = [&](const u16* __restrict__ G, int grow0, int kb, u16* lds) {
#pragma unroll
    for (int li = 0; li < 2; ++li)
      gload_lds16(G + (size_t)grow0 * K + kb + srcOff[li],
                  (u16*)((char*)lds + dstD[li]));
  };

  f32x4 acc[4][4];
#pragma unroll
  for (int m = 0; m < 4; ++m)
#pragma unroll
    for (int n = 0; n < 4; ++n) acc[m][n] = f32x4{0.f, 0.f, 0.f, 0.f};

  const int nk = K >> 6;
  stage(A,  row0,       0,  &AL[0][0][0]);
  stage(A,  row0 + 128, 0,  &AL[0][1][0]);
  stage(Bm, col0,       0,  &BL[0][0]);
  stage(A,  row0,       64, &AL[1][0][0]);
  stage(A,  row0 + 128, 64, &AL[1][1][0]);
  asm volatile("s_waitcnt vmcnt(4)" ::: "memory");
  SBAR();

  for (int t = 0; t < nk; ++t) {
    const int bi = t & 1;
    const bool sB = (t + 1 < nk);
    const bool sA = (t + 2 < nk);
    const char* Ab = (const char*)&AL[bi][wr >> 1][0];
    const int am = (wr & 1) * 4;
    const char* Bb = (const char*)&BL[bi][0];
    const int bn = wc * 4;
    bf16x8 a0[2][2], a1[2][2], b0[2][2], b1[2][2];
#pragma unroll
    for (int kk = 0; kk < 2; ++kk)
#pragma unroll
      for (int m = 0; m < 2; ++m)
        a0[kk][m] = *(const bf16x8*)(Ab + (am + m) * 2048 + kk * 1024 + laneoff);
#pragma unroll
    for (int kk = 0; kk < 2; ++kk)
#pragma unroll
      for (int n = 0; n < 2; ++n)
        b0[kk][n] = *(const bf16x8*)(Bb + (bn + n) * 2048 + kk * 1024 + laneoff);
    if (sB) stage(Bm, col0, (t + 1) * 64, &BL[bi ^ 1][0]);
    SBAR();
    MFMA_GRP2(a0, b0, 0, 0);
    SBAR();
#pragma unroll
    for (int kk = 0; kk < 2; ++kk)
#pragma unroll
      for (int m = 0; m < 2; ++m)
        a1[kk][m] = *(const bf16x8*)(Ab + (am + 2 + m) * 2048 + kk * 1024 + laneoff);
    SBAR();
    MFMA_GRP2(a1, b0, 2, 0);
    SBAR();
#pragma unroll
    for (int kk = 0; kk < 2; ++kk)
#pragma unroll
      for (int n = 0; n < 2; ++n)
        b1[kk][n] = *(const bf16x8*)(Bb + (bn + 2 + n) * 2048 + kk * 1024 + laneoff);
    if (sA) stage(A, row0, (t + 2) * 64, &AL[bi][0][0]);
    SBAR();
    MFMA_GRP2(a1, b1, 2, 2);
    SBAR();
    if (sA) {
      stage(A, row0 + 128, (t + 2) * 64, &AL[bi][1][0]);
      asm volatile("s_waitcnt vmcnt(4)" ::: "memory");
    } else if (sB) {
      asm volatile("s_waitcnt vmcnt(0)" ::: "memory");
    }
    SBAR();
    MFMA_GRP2(a0, b1, 0, 2);
    SBAR();
  }

#pragma unroll
  for (int m = 0; m < 4; ++m) {
    const int r = row0 + wr * 64 + m * 16 + l4 * 4;
#pragma unroll
    for (int n = 0; n < 4; ++n) {
      const int c = col0 + wc * 64 + n * 16 + l15;
#pragma unroll
      for (int j = 0; j < 4; ++j)
        C[(size_t)(r + j) * N + c] = acc[m][n][j];
    }
  }
}

// ---- fused RoPE (Q pre-scaled by scale*log2e) + K RoPE + V transpose ----
__global__ __launch_bounds__(256) void k_ropev(
    const u16* __restrict__ qkv, const float* __restrict__ cs,
    u16* __restrict__ Qr, u16* __restrict__ Kr, u16* __restrict__ Vt)
{
  const int blk = blockIdx.x;            // b*256 + (s>>3)
  const int b = blk >> 8, s0 = (blk & 255) << 3;
  const int tid = threadIdx.x;
  const float S2 = 0.08838834764831845f * 1.4426950408889634f;
#pragma unroll
  for (int p = tid; p < 1024; p += 256) {
    const int s = p >> 7, rem = p & 127, h = rem >> 3, j8 = (rem & 7) * 8;
    const int sg = s0 + s;
    const u16* src = qkv + (size_t)(b * S_LEN + sg) * QKV_N + h * 128 + j8;
    union { uint4 v; u16 u[8]; } lo, hi, olo, ohi;
    lo.v = *(const uint4*)(src);
    hi.v = *(const uint4*)(src + 64);
    const float* cp = cs + (size_t)(sg * 64 + j8) * 2;
#pragma unroll
    for (int k = 0; k < 8; ++k) {
      const float c = cp[k * 2], sn = cp[k * 2 + 1];
      const float x0 = b2f(lo.u[k]), x1 = b2f(hi.u[k]);
      olo.u[k] = f2b((x0 * c - x1 * sn) * S2);
      ohi.u[k] = f2b((x1 * c + x0 * sn) * S2);
    }
    u16* dst = Qr + ((size_t)(b * NHEADS + h) * S_LEN + sg) * HDIM + j8;
    *(uint4*)(dst) = olo.v;
    *(uint4*)(dst + 64) = ohi.v;
  }
  {
    const int p = tid;
    const int s = p >> 5, rem = p & 31, h = rem >> 3, j8 = (rem & 7) * 8;
    const int sg = s0 + s;
    const u16* src = qkv + (size_t)(b * S_LEN + sg) * QKV_N + 2048 + h * 128 + j8;
    union { uint4 v; u16 u[8]; } lo, hi, olo, ohi;
    lo.v = *(const uint4*)(src);
    hi.v = *(const uint4*)(src + 64);
    const float* cp = cs + (size_t)(sg * 64 + j8) * 2;
#pragma unroll
    for (int k = 0; k < 8; ++k) {
      const float c = cp[k * 2], sn = cp[k * 2 + 1];
      const float x0 = b2f(lo.u[k]), x1 = b2f(hi.u[k]);
      olo.u[k] = f2b(x0 * c - x1 * sn);
      ohi.u[k] = f2b(x1 * c + x0 * sn);
    }
    u16* dst = Kr + ((size_t)(b * NKVH + h) * S_LEN + sg) * HDIM + j8;
    *(uint4*)(dst) = olo.v;
    *(uint4*)(dst + 64) = ohi.v;
  }
#pragma unroll
  for (int vi = 0; vi < 2; ++vi) {
    const int idx = vi * 256 + tid, h = idx >> 7, d = idx & 127;
    union { u16 u[8]; uint4 v; } bb;
#pragma unroll
    for (int s = 0; s < 8; ++s)
      bb.u[s] = qkv[(size_t)(b * S_LEN + s0 + s) * QKV_N + 2560 + idx];
    *(uint4*)(Vt + ((size_t)(b * NKVH + h) * HDIM + d) * S_LEN + s0) = bb.v;
  }
}

// ---- flash attention v15 (best measured 78.4 us): v6 per-wave body;
// ---- 512-thr block = 2 heads sharing one KV LDS stream ----
__device__ __forceinline__ void attn_qtile(
    int qt, int lastPhase,
    const u16* __restrict__ Q, const u16* __restrict__ Kg, const u16* __restrict__ Vg,
    u16* __restrict__ Out, int bh,
    u16* Kl0, u16* Kl1, u16* Vl0, u16* Vl1,
    const int (&ko)[2], const int (&vo)[2],
    int wave, int w4, int lane, int& cur)
{
  const int l15 = lane & 15, l4 = lane >> 4;
  const int b = bh >> 4, h = bh & 15;
  const int qw0 = qt * 64 + w4 * 16;
  const u16* Qg = Q + ((size_t)bh * S_LEN + qw0) * HDIM;

  bf16x8 qf[4];
#pragma unroll
  for (int kc = 0; kc < 4; ++kc)
    qf[kc] = *(const bf16x8*)(Qg + l15 * HDIM + kc * 32 + l4 * 8);

  f32x4 zero = {0.f, 0.f, 0.f, 0.f};
  f32x4 oacc[8];
#pragma unroll
  for (int i = 0; i < 8; ++i) oacc[i] = zero;
  float m_r = -1e30f, l_p = 0.f;

  const int nt = qt + 1;
  const int qg = qw0 + l15;

  for (int t = 0; t < nt; ++t) {
    const int kt = t * 64;
    u16* Vb = cur ? Vl1 : Vl0;
#pragma unroll
    for (int it = 0; it < 2; ++it)
      gload_lds16(Vg + (size_t)vo[it] + kt, Vb + (it * 8 + wave) * 512);
    const int hasNext = (t + 1 < nt) || (!lastPhase);
    const int ktn = (t + 1 < nt) ? kt + 64 : 0;
    u16* Kn = cur ? Kl0 : Kl1;
    if (hasNext) {
#pragma unroll
      for (int it = 0; it < 2; ++it)
        gload_lds16(Kg + (size_t)ktn * HDIM + ko[it], Kn + (it * 8 + wave) * 512);
      asm volatile("s_waitcnt vmcnt(4)" ::: "memory");
    } else {
      asm volatile("s_waitcnt vmcnt(2)" ::: "memory");
    }
    SBAR();

    const char* Kb = (const char*)(cur ? Kl1 : Kl0);
    f32x4 s[4];
#pragma unroll
    for (int n = 0; n < 4; ++n) s[n] = zero;
    __builtin_amdgcn_s_setprio(1);
#pragma unroll
    for (int n = 0; n < 4; ++n) {
      const int row = n * 16 + l15;
#pragma unroll
      for (int kc = 0; kc < 4; ++kc) {
        const int ab = (row * 256 + kc * 64 + l4 * 16) ^ ((row & 7) << 4);
        bf16x8 kf = *(const bf16x8*)(Kb + ab);
        s[n] = __builtin_amdgcn_mfma_f32_16x16x32_bf16(kf, qf[kc], s[n], 0, 0, 0);
      }
    }
    __builtin_amdgcn_s_setprio(0);
    float sv[4][4];
    if (kt + 63 > qw0) {
#pragma unroll
      for (int n = 0; n < 4; ++n)
#pragma unroll
        for (int j = 0; j < 4; ++j) {
          float x = s[n][j];
          if (kt + n * 16 + l4 * 4 + j > qg) x = -1e30f;
          sv[n][j] = x;
        }
    } else {
#pragma unroll
      for (int n = 0; n < 4; ++n)
#pragma unroll
        for (int j = 0; j < 4; ++j) sv[n][j] = s[n][j];
    }
    float pm = sv[0][0];
#pragma unroll
    for (int n = 0; n < 4; ++n)
#pragma unroll
      for (int j = 0; j < 4; ++j) pm = fmaxf(pm, sv[n][j]);
    if (!__all(pm <= m_r + 11.5416f)) {
      float pf = fmaxf(pm, __shfl_xor(pm, 16, 64));
      pf = fmaxf(pf, __shfl_xor(pf, 32, 64));
      const float mn = fmaxf(m_r, pf);
      const float sc = exp2f(m_r - mn);
      m_r = mn;
      l_p *= sc;
      float scq[4];
#pragma unroll
      for (int j = 0; j < 4; ++j) scq[j] = __shfl(sc, l4 * 4 + j, 64);
#pragma unroll
      for (int nd = 0; nd < 8; ++nd)
#pragma unroll
        for (int j = 0; j < 4; ++j) oacc[nd][j] *= scq[j];
    }
    union { unsigned u[2]; s16x4 v; } a[4];
#pragma unroll
    for (int n = 0; n < 4; ++n) {
      const float p0 = exp2f(sv[n][0] - m_r);
      const float p1 = exp2f(sv[n][1] - m_r);
      const float p2 = exp2f(sv[n][2] - m_r);
      const float p3 = exp2f(sv[n][3] - m_r);
      l_p += (p0 + p1) + (p2 + p3);
      a[n].u[0] = cvtpk(p0, p1);
      a[n].u[1] = cvtpk(p2, p3);
    }
    if (hasNext) asm volatile("s_waitcnt vmcnt(2)" ::: "memory");
    else         asm volatile("s_waitcnt vmcnt(0)" ::: "memory");
    SBAR();
    __builtin_amdgcn_s_setprio(1);
#pragma unroll
    for (int nd = 0; nd < 8; ++nd) {
      const int d = nd * 16 + l15;
      const int rowb = d * 128, swz = (d & 7) << 4;
#pragma unroll
      for (int n = 0; n < 4; ++n) {
        const int ab = (rowb + n * 32 + l4 * 8) ^ swz;
        s16x4 vf = *(const s16x4*)((const char*)Vb + ab);
        oacc[nd] = mfma16(a[n].v, vf, oacc[nd]);
      }
    }
    __builtin_amdgcn_s_setprio(0);
    cur ^= 1;
  }

  l_p += __shfl_xor(l_p, 16, 64);
  l_p += __shfl_xor(l_p, 32, 64);
  float il[4];
#pragma unroll
  for (int j = 0; j < 4; ++j) il[j] = 1.f / __shfl(l_p, l4 * 4 + j, 64);
  const size_t obase = ((size_t)b * S_LEN + qw0 + l4 * 4) * HID + h * HDIM;
#pragma unroll
  for (int nd = 0; nd < 8; ++nd)
#pragma unroll
    for (int j = 0; j < 4; ++j)
      Out[obase + (size_t)j * HID + nd * 16 + l15] = f2b(oacc[nd][j] * il[j]);
}

__global__ __launch_bounds__(512) void k_attn(
    const u16* __restrict__ Q, const u16* __restrict__ Kr,
    const u16* __restrict__ Vt, u16* __restrict__ Out)
{
  __shared__ u16 Kl[2][64 * 128];   // 32 KB dbuf, XOR ^((kv&7)<<4)
  __shared__ u16 Vl[2][128 * 64];   // 32 KB dbuf, XOR ^((d&7)<<4)
  const int tid = threadIdx.x;
  const int wave = tid >> 6, lane = tid & 63;
  const int bx = blockIdx.x;              // hp*8 + b*4 + kvh : XCD = bx%8
  const int pairi = blockIdx.y;           // pair (31-pairi, pairi)
  const int kvh = bx & 3, b = (bx >> 2) & 1, hp = bx >> 3;
  const int h = kvh * 4 + hp + (wave >> 2) * 2;   // waves 0-3: h, 4-7: h+2
  const int bh = b * NHEADS + h;
  const int w4 = wave & 3;

  const u16* Kg = Kr + (size_t)(b * NKVH + kvh) * S_LEN * HDIM;
  const u16* Vg = Vt + (size_t)(b * NKVH + kvh) * HDIM * S_LEN;

  int ko[2], vo[2];
#pragma unroll
  for (int it = 0; it < 2; ++it) {
    const int c = it * 8 + wave;
    const int L = c * 1024 + lane * 16;
    const int r = L >> 8;  const int w2 = (L & 255) ^ ((r & 7) << 4);
    ko[it] = r * HDIM + (w2 >> 1);
    const int d = L >> 7;  const int wv = (L & 127) ^ ((d & 7) << 4);
    vo[it] = d * S_LEN + (wv >> 1);
  }
#pragma unroll
  for (int it = 0; it < 2; ++it)
    gload_lds16(Kg + ko[it], &Kl[0][(it * 8 + wave) * 512]);

  int cur = 0;
  attn_qtile(31 - pairi, 0, Q, Kg, Vg, Out, bh, &Kl[0][0], &Kl[1][0],
             &Vl[0][0], &Vl[1][0], ko, vo, wave, w4, lane, cur);
  attn_qtile(pairi,      1, Q, Kg, Vg, Out, bh, &Kl[0][0], &Kl[1][0],
             &Vl[0][0], &Vl[1][0], ko, vo, wave, w4, lane, cur);
}

extern "C" void kernel_launch(void* const* d_in, const int* in_sizes, int n_in,
                              void* d_out, int out_size, void* d_ws, size_t ws_size,
                              hipStream_t stream)
{
  const float* x  = (const float*)d_in[0];
  const float* Wq = (const float*)d_in[2];
  const float* Wk = (const float*)d_in[3];
  const float* Wv = (const float*)d_in[4];
  const float* Wo = (const float*)d_in[5];
  float* out = (float*)d_out;

  u16* xb    = (u16*)d_ws;
  u16* Wqkvb = xb    + (size_t)MROWS * HID;
  u16* Wob   = Wqkvb + (size_t)QKV_N * HID;
  u16* qkv   = Wob   + (size_t)HID * HID;
  u16* Qr    = qkv   + (size_t)MROWS * QKV_N;
  u16* Kr    = Qr    + (size_t)BB * NHEADS * S_LEN * HDIM;
  u16* Vt    = Kr    + (size_t)BB * NKVH * S_LEN * HDIM;
  u16* attn  = Vt    + (size_t)BB * NKVH * S_LEN * HDIM;
  float* cs  = (float*)(attn + (size_t)MROWS * HID);

  k_prep<<<dim3(PB_CS), 256, 0, stream>>>(x, Wq, Wk, Wv, Wo, xb, Wqkvb, Wob, cs);
  k_gemm_qkv<<<dim3(QKV_N / 192, MROWS / 256), 512, 0, stream>>>(xb, Wqkvb, qkv, MROWS, QKV_N, HID);
  k_ropev<<<dim3(BB * 256), 256, 0, stream>>>(qkv, cs, Qr, Kr, Vt);
  k_attn<<<dim3(16, 16), 512, 0, stream>>>(Qr, Kr, Vt, attn);
  k_gemm_op<<<dim3(HID / 128, MROWS / 256), 512, 0, stream>>>(attn, Wob, out, MROWS, HID, HID);
}

// Round 20
// 198.519 us; speedup vs baseline: 1.0602x; 1.0060x over previous
//
#include <hip/hip_runtime.h>

typedef unsigned short u16;
typedef __bf16 bf16x8 __attribute__((ext_vector_type(8)));
typedef float f32x4 __attribute__((ext_vector_type(4)));
typedef short s16x4 __attribute__((ext_vector_type(4)));

#define S_LEN  2048
#define NHEADS 16
#define NKVH   4
#define HDIM   128
#define BB     2
#define MROWS  4096   // B*S
#define QKV_N  3072   // NH*HD + 2*NKV*HD
#define HID    2048

__device__ __forceinline__ u16 f2b(float f) {
  union { float f; unsigned u; } x; x.f = f;
  unsigned r = x.u + 0x7fffu + ((x.u >> 16) & 1u);
  return (u16)(r >> 16);
}
__device__ __forceinline__ float b2f(u16 v) {
  union { unsigned u; float f; } x; x.u = ((unsigned)v) << 16;
  return x.f;
}
__device__ __forceinline__ void gload_lds16(const u16* g, u16* l) {
  __builtin_amdgcn_global_load_lds((__attribute__((address_space(1))) void*)g,
                                   (__attribute__((address_space(3))) void*)l,
                                   16, 0, 0);
}
__device__ __forceinline__ unsigned cvtpk(float lo, float hi) {
  unsigned r;
  asm("v_cvt_pk_bf16_f32 %0, %1, %2" : "=v"(r) : "v"(lo), "v"(hi));
  return r;
}
#if __has_builtin(__builtin_amdgcn_mfma_f32_16x16x16bf16_1k)
__device__ __forceinline__ f32x4 mfma16(s16x4 a, s16x4 b, f32x4 c) {
  return __builtin_amdgcn_mfma_f32_16x16x16bf16_1k(a, b, c, 0, 0, 0);
}
#else
__device__ __forceinline__ f32x4 mfma16(s16x4 a, s16x4 b, f32x4 c) {
  asm("v_mfma_f32_16x16x16_bf16 %0, %1, %2, %0" : "+v"(c) : "v"(a), "v"(b));
  return c;
}
#endif

#define SBAR() do { __builtin_amdgcn_sched_barrier(0); \
                    __builtin_amdgcn_s_barrier();      \
                    __builtin_amdgcn_sched_barrier(0); } while (0)

// ---- one-launch prep: all fp32->bf16 converts + RoPE cos/sin table ----
#define PB_X   8192
#define PB_WQ  (PB_X + 4096)
#define PB_WK  (PB_WQ + 1024)
#define PB_WV  (PB_WK + 1024)
#define PB_WO  (PB_WV + 4096)
#define PB_CS  (PB_WO + 512)
__global__ void k_prep(const float* __restrict__ x,
                       const float* __restrict__ Wq, const float* __restrict__ Wk,
                       const float* __restrict__ Wv, const float* __restrict__ Wo,
                       u16* __restrict__ xb, u16* __restrict__ Wqkvb,
                       u16* __restrict__ Wob, float* __restrict__ cs)
{
  const int bid = blockIdx.x, tid = threadIdx.x;
  const float* src; u16* dst; int i;
  if (bid < PB_X)       { i = bid * 256 + tid;            src = x;  dst = xb; }
  else if (bid < PB_WQ) { i = (bid - PB_X) * 256 + tid;   src = Wq; dst = Wqkvb; }
  else if (bid < PB_WK) { i = (bid - PB_WQ) * 256 + tid;  src = Wk; dst = Wqkvb + (size_t)2048 * HID; }
  else if (bid < PB_WV) { i = (bid - PB_WK) * 256 + tid;  src = Wv; dst = Wqkvb + (size_t)2560 * HID; }
  else if (bid < PB_WO) { i = (bid - PB_WV) * 256 + tid;  src = Wo; dst = Wob; }
  else {
    const int p = (bid - PB_WO) * 256 + tid;
    const int s = p >> 6, j = p & 63;
    float inv = expf(-(float)j * 0.14391156831212787f);
    float ang = (float)s * inv;
    float c, sn; sincosf(ang, &sn, &c);
    cs[p * 2 + 0] = c; cs[p * 2 + 1] = sn;
    return;
  }
  float4 v = ((const float4*)src)[i];
  ushort4 o;
  o.x = f2b(v.x); o.y = f2b(v.y); o.z = f2b(v.z); o.w = f2b(v.w);
  ((ushort4*)dst)[i] = o;
}

// ======================================================================
// 256x192-tile 8-phase GEMM (QKV): grid 16x16 = 256 blocks = 1/CU.
// ======================================================================
#define MFMA_G3(AV, NLO, NHI, MO)                                             \
  __builtin_amdgcn_s_setprio(1);                                              \
  _Pragma("unroll") for (int kk = 0; kk < 2; ++kk)                            \
  _Pragma("unroll") for (int mm = 0; mm < 4; ++mm)                            \
  _Pragma("unroll") for (int nn = (NLO); nn <= (NHI); ++nn)                   \
    acc[(MO) + mm][nn] = __builtin_amdgcn_mfma_f32_16x16x32_bf16(             \
        AV[kk][mm], bfr[kk][nn], acc[(MO) + mm][nn], 0, 0, 0);                \
  __builtin_amdgcn_s_setprio(0);

__global__ __launch_bounds__(512, 1) void k_gemm_qkv(
    const u16* __restrict__ A, const u16* __restrict__ Bm,
    u16* __restrict__ C, int M, int N, int K)
{
  __shared__ u16 AL[2][2][8192];   // 64 KB
  __shared__ u16 BL[2][12288];     // 48 KB
  const int tid = threadIdx.x;
  const int wave = tid >> 6, lane = tid & 63;
  const int l15 = lane & 15, l4 = lane >> 4;
  const int wr = wave >> 2, wc = wave & 3;   // 2 M x 4 N
  const int gx = gridDim.x;                  // 16 = N/192
  const int nwg = gx * gridDim.y;            // 256
  int bid = blockIdx.y * gx + blockIdx.x;
  bid = (bid & 7) * (nwg >> 3) + (bid >> 3);
  const int col0 = (bid % gx) * 192, row0 = (bid / gx) * 256;

  int soA[2], dA[2], soB[3], dB[3];
#pragma unroll
  for (int li = 0; li < 3; ++li) {
    const int D = (li * 512 + tid) * 16;
    const int off_p = D & 1023, si = D >> 10;
    const int off_l = off_p ^ (((off_p >> 9) & 1) << 5);
    const int R = si >> 1, Cc = si & 1;
    const int row = R * 16 + (off_l >> 6);
    const int colb = Cc * 64 + (off_l & 63);
    const int so = row * K + (colb >> 1);
    if (li < 2) { soA[li] = so; dA[li] = D; }
    soB[li] = so; dB[li] = D;
  }
  const int laneoff = (l15 * 64 + l4 * 16) ^ ((l15 >> 3) << 5);

  auto stageA = [&](int grow0, int kb, u16* lds) {
#pragma unroll
    for (int li = 0; li < 2; ++li)
      gload_lds16(A + (size_t)grow0 * K + kb + soA[li],
                  (u16*)((char*)lds + dA[li]));
  };
  auto stageB = [&](int kb, u16* lds) {
#pragma unroll
    for (int li = 0; li < 3; ++li)
      gload_lds16(Bm + (size_t)col0 * K + kb + soB[li],
                  (u16*)((char*)lds + dB[li]));
  };

  f32x4 acc[8][3];
#pragma unroll
  for (int m = 0; m < 8; ++m)
#pragma unroll
    for (int n = 0; n < 3; ++n) acc[m][n] = f32x4{0.f, 0.f, 0.f, 0.f};

  const int nk = K >> 6;
  stageA(row0,       0,  &AL[0][0][0]);
  stageA(row0 + 128, 0,  &AL[0][1][0]);
  stageB(0, &BL[0][0]);
  stageA(row0,       64, &AL[1][0][0]);
  stageA(row0 + 128, 64, &AL[1][1][0]);
  asm volatile("s_waitcnt vmcnt(4)" ::: "memory");
  SBAR();

  for (int t = 0; t < nk; ++t) {
    const int bi = t & 1;
    const bool sB = (t + 1 < nk);
    const bool sA = (t + 2 < nk);
    const char* Ab = (const char*)&AL[bi][wr][0];
    const char* Bb = (const char*)&BL[bi][0] + wc * 6144;
    bf16x8 a0[2][4], a1[2][4], bfr[2][3];
#pragma unroll
    for (int kk = 0; kk < 2; ++kk)
#pragma unroll
      for (int m = 0; m < 4; ++m)
        a0[kk][m] = *(const bf16x8*)(Ab + m * 2048 + kk * 1024 + laneoff);
#pragma unroll
    for (int kk = 0; kk < 2; ++kk)
#pragma unroll
      for (int n = 0; n < 3; ++n)
        bfr[kk][n] = *(const bf16x8*)(Bb + n * 2048 + kk * 1024 + laneoff);
    if (sB) stageB((t + 1) * 64, &BL[bi ^ 1][0]);
    SBAR();
    MFMA_G3(a0, 0, 1, 0);
    SBAR();
#pragma unroll
    for (int kk = 0; kk < 2; ++kk)
#pragma unroll
      for (int m = 0; m < 4; ++m)
        a1[kk][m] = *(const bf16x8*)(Ab + (m + 4) * 2048 + kk * 1024 + laneoff);
    SBAR();
    MFMA_G3(a1, 0, 1, 4);
    SBAR();
    if (sA) stageA(row0, (t + 2) * 64, &AL[bi][0][0]);
    SBAR();
    MFMA_G3(a1, 2, 2, 4);
    SBAR();
    if (sA) {
      stageA(row0 + 128, (t + 2) * 64, &AL[bi][1][0]);
      asm volatile("s_waitcnt vmcnt(4)" ::: "memory");
    } else if (sB) {
      asm volatile("s_waitcnt vmcnt(0)" ::: "memory");
    }
    SBAR();
    MFMA_G3(a0, 2, 2, 0);
    SBAR();
  }

#pragma unroll
  for (int m = 0; m < 8; ++m) {
    const int r = row0 + wr * 128 + m * 16 + l4 * 4;
#pragma unroll
    for (int n = 0; n < 3; ++n) {
      const int c = col0 + wc * 48 + n * 16 + l15;
#pragma unroll
      for (int j = 0; j < 4; ++j)
        C[(size_t)(r + j) * N + c] = f2b(acc[m][n][j]);
    }
  }
}

// ======================================================================
// 256x128-tile 8-phase GEMM (out-proj): grid 16x16 = 256 blocks = 1/CU.
// ======================================================================
#define MFMA_GRP2(AV, BV, MO, NO)                                             \
  __builtin_amdgcn_s_setprio(1);                                              \
  _Pragma("unroll") for (int kk = 0; kk < 2; ++kk)                            \
  _Pragma("unroll") for (int mm = 0; mm < 2; ++mm)                            \
  _Pragma("unroll") for (int nn = 0; nn < 2; ++nn)                            \
    acc[(MO) + mm][(NO) + nn] = __builtin_amdgcn_mfma_f32_16x16x32_bf16(      \
        AV[kk][mm], BV[kk][nn], acc[(MO) + mm][(NO) + nn], 0, 0, 0);          \
  __builtin_amdgcn_s_setprio(0);

__global__ __launch_bounds__(512, 1) void k_gemm_op(
    const u16* __restrict__ A, const u16* __restrict__ Bm,
    float* __restrict__ C, int M, int N, int K)
{
  __shared__ u16 AL[2][2][8192];   // 64 KB
  __shared__ u16 BL[2][8192];      // 32 KB
  const int tid = threadIdx.x;
  const int wave = tid >> 6, lane = tid & 63;
  const int l15 = lane & 15, l4 = lane >> 4;
  const int wr = wave >> 1, wc = wave & 1;
  const int gx = gridDim.x;
  const int nwg = gx * gridDim.y;
  int bid = blockIdx.y * gx + blockIdx.x;
  bid = (bid & 7) * (nwg >> 3) + (bid >> 3);
  const int col0 = (bid % gx) * 128, row0 = (bid / gx) * 256;

  int srcOff[2], dstD[2];
#pragma unroll
  for (int li = 0; li < 2; ++li) {
    const int D = (li * 512 + tid) * 16;
    const int off_p = D & 1023, si = D >> 10;
    const int off_l = off_p ^ (((off_p >> 9) & 1) << 5);
    const int R = si >> 1, Cc = si & 1;
    const int row = R * 16 + (off_l >> 6);
    const int colb = Cc * 64 + (off_l & 63);
    srcOff[li] = row * K + (colb >> 1);
    dstD[li] = D;
  }
  const int laneoff = (l15 * 64 + l4 * 16) ^ ((l15 >> 3) << 5);

  auto stage = [&](const u16* __restrict__ G, int grow0, int kb, u16* lds) {
#pragma unroll
    for (int li = 0; li < 2; ++li)
      gload_lds16(G + (size_t)grow0 * K + kb + srcOff[li],
                  (u16*)((char*)lds + dstD[li]));
  };

  f32x4 acc[4][4];
#pragma unroll
  for (int m = 0; m < 4; ++m)
#pragma unroll
    for (int n = 0; n < 4; ++n) acc[m][n] = f32x4{0.f, 0.f, 0.f, 0.f};

  const int nk = K >> 6;
  stage(A,  row0,       0,  &AL[0][0][0]);
  stage(A,  row0 + 128, 0,  &AL[0][1][0]);
  stage(Bm, col0,       0,  &BL[0][0]);
  stage(A,  row0,       64, &AL[1][0][0]);
  stage(A,  row0 + 128, 64, &AL[1][1][0]);
  asm volatile("s_waitcnt vmcnt(4)" ::: "memory");
  SBAR();

  for (int t = 0; t < nk; ++t) {
    const int bi = t & 1;
    const bool sB = (t + 1 < nk);
    const bool sA = (t + 2 < nk);
    const char* Ab = (const char*)&AL[bi][wr >> 1][0];
    const int am = (wr & 1) * 4;
    const char* Bb = (const char*)&BL[bi][0];
    const int bn = wc * 4;
    bf16x8 a0[2][2], a1[2][2], b0[2][2], b1[2][2];
#pragma unroll
    for (int kk = 0; kk < 2; ++kk)
#pragma unroll
      for (int m = 0; m < 2; ++m)
        a0[kk][m] = *(const bf16x8*)(Ab + (am + m) * 2048 + kk * 1024 + laneoff);
#pragma unroll
    for (int kk = 0; kk < 2; ++kk)
#pragma unroll
      for (int n = 0; n < 2; ++n)
        b0[kk][n] = *(const bf16x8*)(Bb + (bn + n) * 2048 + kk * 1024 + laneoff);
    if (sB) stage(Bm, col0, (t + 1) * 64, &BL[bi ^ 1][0]);
    SBAR();
    MFMA_GRP2(a0, b0, 0, 0);
    SBAR();
#pragma unroll
    for (int kk = 0; kk < 2; ++kk)
#pragma unroll
      for (int m = 0; m < 2; ++m)
        a1[kk][m] = *(const bf16x8*)(Ab + (am + 2 + m) * 2048 + kk * 1024 + laneoff);
    SBAR();
    MFMA_GRP2(a1, b0, 2, 0);
    SBAR();
#pragma unroll
    for (int kk = 0; kk < 2; ++kk)
#pragma unroll
      for (int n = 0; n < 2; ++n)
        b1[kk][n] = *(const bf16x8*)(Bb + (bn + 2 + n) * 2048 + kk * 1024 + laneoff);
    if (sA) stage(A, row0, (t + 2) * 64, &AL[bi][0][0]);
    SBAR();
    MFMA_GRP2(a1, b1, 2, 2);
    SBAR();
    if (sA) {
      stage(A, row0 + 128, (t + 2) * 64, &AL[bi][1][0]);
      asm volatile("s_waitcnt vmcnt(4)" ::: "memory");
    } else if (sB) {
      asm volatile("s_waitcnt vmcnt(0)" ::: "memory");
    }
    SBAR();
    MFMA_GRP2(a0, b1, 0, 2);
    SBAR();
  }

#pragma unroll
  for (int m = 0; m < 4; ++m) {
    const int r = row0 + wr * 64 + m * 16 + l4 * 4;
#pragma unroll
    for (int n = 0; n < 4; ++n) {
      const int c = col0 + wc * 64 + n * 16 + l15;
#pragma unroll
      for (int j = 0; j < 4; ++j)
        C[(size_t)(r + j) * N + c] = acc[m][n][j];
    }
  }
}

// ---- fused RoPE (Q pre-scaled by scale*log2e) + K RoPE + V transpose ----
__global__ __launch_bounds__(256) void k_ropev(
    const u16* __restrict__ qkv, const float* __restrict__ cs,
    u16* __restrict__ Qr, u16* __restrict__ Kr, u16* __restrict__ Vt)
{
  const int blk = blockIdx.x;            // b*256 + (s>>3)
  const int b = blk >> 8, s0 = (blk & 255) << 3;
  const int tid = threadIdx.x;
  const float S2 = 0.08838834764831845f * 1.4426950408889634f;
#pragma unroll
  for (int p = tid; p < 1024; p += 256) {
    const int s = p >> 7, rem = p & 127, h = rem >> 3, j8 = (rem & 7) * 8;
    const int sg = s0 + s;
    const u16* src = qkv + (size_t)(b * S_LEN + sg) * QKV_N + h * 128 + j8;
    union { uint4 v; u16 u[8]; } lo, hi, olo, ohi;
    lo.v = *(const uint4*)(src);
    hi.v = *(const uint4*)(src + 64);
    const float* cp = cs + (size_t)(sg * 64 + j8) * 2;
#pragma unroll
    for (int k = 0; k < 8; ++k) {
      const float c = cp[k * 2], sn = cp[k * 2 + 1];
      const float x0 = b2f(lo.u[k]), x1 = b2f(hi.u[k]);
      olo.u[k] = f2b((x0 * c - x1 * sn) * S2);
      ohi.u[k] = f2b((x1 * c + x0 * sn) * S2);
    }
    u16* dst = Qr + ((size_t)(b * NHEADS + h) * S_LEN + sg) * HDIM + j8;
    *(uint4*)(dst) = olo.v;
    *(uint4*)(dst + 64) = ohi.v;
  }
  {
    const int p = tid;
    const int s = p >> 5, rem = p & 31, h = rem >> 3, j8 = (rem & 7) * 8;
    const int sg = s0 + s;
    const u16* src = qkv + (size_t)(b * S_LEN + sg) * QKV_N + 2048 + h * 128 + j8;
    union { uint4 v; u16 u[8]; } lo, hi, olo, ohi;
    lo.v = *(const uint4*)(src);
    hi.v = *(const uint4*)(src + 64);
    const float* cp = cs + (size_t)(sg * 64 + j8) * 2;
#pragma unroll
    for (int k = 0; k < 8; ++k) {
      const float c = cp[k * 2], sn = cp[k * 2 + 1];
      const float x0 = b2f(lo.u[k]), x1 = b2f(hi.u[k]);
      olo.u[k] = f2b(x0 * c - x1 * sn);
      ohi.u[k] = f2b(x1 * c + x0 * sn);
    }
    u16* dst = Kr + ((size_t)(b * NKVH + h) * S_LEN + sg) * HDIM + j8;
    *(uint4*)(dst) = olo.v;
    *(uint4*)(dst + 64) = ohi.v;
  }
#pragma unroll
  for (int vi = 0; vi < 2; ++vi) {
    const int idx = vi * 256 + tid, h = idx >> 7, d = idx & 127;
    union { u16 u[8]; uint4 v; } bb;
#pragma unroll
    for (int s = 0; s < 8; ++s)
      bb.u[s] = qkv[(size_t)(b * S_LEN + s0 + s) * QKV_N + 2560 + idx];
    *(uint4*)(Vt + ((size_t)(b * NKVH + h) * HDIM + d) * S_LEN + s0) = bb.v;
  }
}

// ---- flash attention v17: KVBLK=128 (halved iteration count; fixed
// ---- per-iter cost dominates per KVBLK sweep), single barrier/iter,
// ---- 512-thr block = 2 heads sharing KV stream, 128 KB LDS, 1 block/CU ----
__device__ __forceinline__ void attn_qtile(
    int qt,
    const u16* __restrict__ Q, const u16* __restrict__ Kg, const u16* __restrict__ Vg,
    u16* __restrict__ Out, int bh,
    u16* Kl0, u16* Kl1, u16* Vl0, u16* Vl1,
    const int (&ko)[4], const int (&vo)[4],
    int wave, int w4, int lane, int& cur)
{
  const int l15 = lane & 15, l4 = lane >> 4;
  const int b = bh >> 4, h = bh & 15;
  const int qw0 = qt * 64 + w4 * 16;
  const u16* Qg = Q + ((size_t)bh * S_LEN + qw0) * HDIM;

  bf16x8 qf[4];
#pragma unroll
  for (int kc = 0; kc < 4; ++kc)
    qf[kc] = *(const bf16x8*)(Qg + l15 * HDIM + kc * 32 + l4 * 8);

  f32x4 zero = {0.f, 0.f, 0.f, 0.f};
  f32x4 oacc[8];
#pragma unroll
  for (int i = 0; i < 8; ++i) oacc[i] = zero;
  float m_r = -1e30f, l_p = 0.f;   // per-lane row state for q = qw0 + l15

  const int nt = (qt + 2) >> 1;    // ceil((qt+1)*64 / 128)
  const int qg = qw0 + l15;

  // prologue: issue K(0), V(0) into buffer cur (4 chunks each per wave)
  {
    u16* Kb0 = cur ? Kl1 : Kl0;
    u16* Vb0 = cur ? Vl1 : Vl0;
#pragma unroll
    for (int it = 0; it < 4; ++it)
      gload_lds16(Kg + ko[it], Kb0 + (it * 8 + wave) * 512);
#pragma unroll
    for (int it = 0; it < 4; ++it)
      gload_lds16(Vg + (size_t)vo[it], Vb0 + (it * 8 + wave) * 512);
  }

  for (int t = 0; t < nt; ++t) {
    const int kt = t * 128;
    // single wait+barrier per tile: own K(t)+V(t) loads drained, published
    asm volatile("s_waitcnt vmcnt(0)" ::: "memory");
    SBAR();
    const char* Kb = (const char*)(cur ? Kl1 : Kl0);
    const char* Vb = (const char*)(cur ? Vl1 : Vl0);
    // ---- S^T = K Q^T : lane owns q=l15, k = 16n + 4*l4 + j, n=0..7 ----
    f32x4 s[8];
#pragma unroll
    for (int n = 0; n < 8; ++n) s[n] = zero;
    __builtin_amdgcn_s_setprio(1);
#pragma unroll
    for (int n = 0; n < 8; ++n) {
      const int row = n * 16 + l15;
#pragma unroll
      for (int kc = 0; kc < 4; ++kc) {
        const int ab = (row * 256 + kc * 64 + l4 * 16) ^ ((row & 7) << 4);
        bf16x8 kf = *(const bf16x8*)(Kb + ab);
        s[n] = __builtin_amdgcn_mfma_f32_16x16x32_bf16(kf, qf[kc], s[n], 0, 0, 0);
      }
    }
    __builtin_amdgcn_s_setprio(0);
    // ---- issue K(t+1), V(t+1) into other buffers (readers passed barrier) ----
    if (t + 1 < nt) {
      const int ktn = kt + 128;
      u16* Kn = cur ? Kl0 : Kl1;
      u16* Vn = cur ? Vl0 : Vl1;
#pragma unroll
      for (int it = 0; it < 4; ++it)
        gload_lds16(Kg + (size_t)ktn * HDIM + ko[it], Kn + (it * 8 + wave) * 512);
#pragma unroll
      for (int it = 0; it < 4; ++it)
        gload_lds16(Vg + (size_t)vo[it] + ktn, Vn + (it * 8 + wave) * 512);
    }
    // ---- (rare) causal mask ----
    if (kt + 127 > qw0) {
#pragma unroll
      for (int n = 0; n < 8; ++n)
#pragma unroll
        for (int j = 0; j < 4; ++j)
          if (kt + n * 16 + l4 * 4 + j > qg) s[n][j] = -1e30f;
    }
    float pm = s[0][0];
#pragma unroll
    for (int n = 0; n < 8; ++n)
#pragma unroll
      for (int j = 0; j < 4; ++j) pm = fmaxf(pm, s[n][j]);
    // ---- defer-max ----
    if (!__all(pm <= m_r + 11.5416f)) {
      float pf = fmaxf(pm, __shfl_xor(pm, 16, 64));
      pf = fmaxf(pf, __shfl_xor(pf, 32, 64));
      const float mn = fmaxf(m_r, pf);
      const float sc = exp2f(m_r - mn);
      m_r = mn;
      l_p *= sc;
      float scq[4];
#pragma unroll
      for (int j = 0; j < 4; ++j) scq[j] = __shfl(sc, l4 * 4 + j, 64);
#pragma unroll
      for (int nd = 0; nd < 8; ++nd)
#pragma unroll
        for (int j = 0; j < 4; ++j) oacc[nd][j] *= scq[j];
    }
    // ---- P = exp2(s - m), pack to bf16 A-frags ----
    union { unsigned u[2]; s16x4 v; } a[8];
#pragma unroll
    for (int n = 0; n < 8; ++n) {
      const float p0 = exp2f(s[n][0] - m_r);
      const float p1 = exp2f(s[n][1] - m_r);
      const float p2 = exp2f(s[n][2] - m_r);
      const float p3 = exp2f(s[n][3] - m_r);
      l_p += (p0 + p1) + (p2 + p3);
      a[n].u[0] = cvtpk(p0, p1);
      a[n].u[1] = cvtpk(p2, p3);
    }
    // ---- O += P V (V published at this tile's top barrier) ----
    __builtin_amdgcn_s_setprio(1);
#pragma unroll
    for (int nd = 0; nd < 8; ++nd) {
      const int d = nd * 16 + l15;
      const int rowb = d * 256, swz = (d & 7) << 4;
#pragma unroll
      for (int n = 0; n < 8; ++n) {
        const int ab = (rowb + n * 32 + l4 * 8) ^ swz;
        s16x4 vf = *(const s16x4*)(Vb + ab);
        oacc[nd] = mfma16(a[n].v, vf, oacc[nd]);
      }
    }
    __builtin_amdgcn_s_setprio(0);
    cur ^= 1;
  }

  // ---- epilogue ----
  l_p += __shfl_xor(l_p, 16, 64);
  l_p += __shfl_xor(l_p, 32, 64);
  float il[4];
#pragma unroll
  for (int j = 0; j < 4; ++j) il[j] = 1.f / __shfl(l_p, l4 * 4 + j, 64);
  const size_t obase = ((size_t)b * S_LEN + qw0 + l4 * 4) * HID + h * HDIM;
#pragma unroll
  for (int nd = 0; nd < 8; ++nd)
#pragma unroll
    for (int j = 0; j < 4; ++j)
      Out[obase + (size_t)j * HID + nd * 16 + l15] = f2b(oacc[nd][j] * il[j]);
  // all PV reads of this call consumed before any next-call prologue write
  SBAR();
}

__global__ __launch_bounds__(512) void k_attn(
    const u16* __restrict__ Q, const u16* __restrict__ Kr,
    const u16* __restrict__ Vt, u16* __restrict__ Out)
{
  __shared__ u16 Kl[2][128 * 128];   // 64 KB dbuf: [kv][d], XOR ^((kv&7)<<4)
  __shared__ u16 Vl[2][128 * 128];   // 64 KB dbuf: [d][kv], XOR ^((d&7)<<4)
  const int tid = threadIdx.x;
  const int wave = tid >> 6, lane = tid & 63;
  const int bx = blockIdx.x;              // hp*8 + b*4 + kvh : XCD = bx%8
  const int pairi = blockIdx.y;           // pair (31-pairi, pairi): 17 tiles
  const int kvh = bx & 3, b = (bx >> 2) & 1, hp = bx >> 3;
  const int h = kvh * 4 + hp + (wave >> 2) * 2;   // waves 0-3: h, 4-7: h+2
  const int bh = b * NHEADS + h;
  const int w4 = wave & 3;

  const u16* Kg = Kr + (size_t)(b * NKVH + kvh) * S_LEN * HDIM;
  const u16* Vg = Vt + (size_t)(b * NKVH + kvh) * HDIM * S_LEN;

  // staging offsets (rule 21): 32 chunks of 1 KB, c = it*8 + wave
  int ko[4], vo[4];
#pragma unroll
  for (int it = 0; it < 4; ++it) {
    const int c = it * 8 + wave;
    const int L = c * 1024 + lane * 16;
    const int r = L >> 8;  const int w2 = (L & 255) ^ ((r & 7) << 4);
    ko[it] = r * HDIM + (w2 >> 1);
    const int d = L >> 8;  const int wv = (L & 255) ^ ((d & 7) << 4);
    vo[it] = d * S_LEN + (wv >> 1);
  }

  int cur = 0;
  attn_qtile(31 - pairi, Q, Kg, Vg, Out, bh, &Kl[0][0], &Kl[1][0],
             &Vl[0][0], &Vl[1][0], ko, vo, wave, w4, lane, cur);
  attn_qtile(pairi,      Q, Kg, Vg, Out, bh, &Kl[0][0], &Kl[1][0],
             &Vl[0][0], &Vl[1][0], ko, vo, wave, w4, lane, cur);
}

extern "C" void kernel_launch(void* const* d_in, const int* in_sizes, int n_in,
                              void* d_out, int out_size, void* d_ws, size_t ws_size,
                              hipStream_t stream)
{
  const float* x  = (const float*)d_in[0];
  const float* Wq = (const float*)d_in[2];
  const float* Wk = (const float*)d_in[3];
  const float* Wv = (const float*)d_in[4];
  const float* Wo = (const float*)d_in[5];
  float* out = (float*)d_out;

  u16* xb    = (u16*)d_ws;
  u16* Wqkvb = xb    + (size_t)MROWS * HID;
  u16* Wob   = Wqkvb + (size_t)QKV_N * HID;
  u16* qkv   = Wob   + (size_t)HID * HID;
  u16* Qr    = qkv   + (size_t)MROWS * QKV_N;
  u16* Kr    = Qr    + (size_t)BB * NHEADS * S_LEN * HDIM;
  u16* Vt    = Kr    + (size_t)BB * NKVH * S_LEN * HDIM;
  u16* attn  = Vt    + (size_t)BB * NKVH * S_LEN * HDIM;
  float* cs  = (float*)(attn + (size_t)MROWS * HID);

  k_prep<<<dim3(PB_CS), 256, 0, stream>>>(x, Wq, Wk, Wv, Wo, xb, Wqkvb, Wob, cs);
  k_gemm_qkv<<<dim3(QKV_N / 192, MROWS / 256), 512, 0, stream>>>(xb, Wqkvb, qkv, MROWS, QKV_N, HID);
  k_ropev<<<dim3(BB * 256), 256, 0, stream>>>(qkv, cs, Qr, Kr, Vt);
  k_attn<<<dim3(16, 16), 512, 0, stream>>>(Qr, Kr, Vt, attn);
  k_gemm_op<<<dim3(HID / 128, MROWS / 256), 512, 0, stream>>>(attn, Wob, out, MROWS, HID, HID);
}

// Round 21
// 195.498 us; speedup vs baseline: 1.0766x; 1.0155x over previous
//
#include <hip/hip_runtime.h>

typedef unsigned short u16;
typedef __bf16 bf16x8 __attribute__((ext_vector_type(8)));
typedef float f32x4 __attribute__((ext_vector_type(4)));
typedef short s16x4 __attribute__((ext_vector_type(4)));

#define S_LEN  2048
#define NHEADS 16
#define NKVH   4
#define HDIM   128
#define BB     2
#define MROWS  4096   // B*S
#define QKV_N  3072   // NH*HD + 2*NKV*HD
#define HID    2048

__device__ __forceinline__ u16 f2b(float f) {
  union { float f; unsigned u; } x; x.f = f;
  unsigned r = x.u + 0x7fffu + ((x.u >> 16) & 1u);
  return (u16)(r >> 16);
}
__device__ __forceinline__ float b2f(u16 v) {
  union { unsigned u; float f; } x; x.u = ((unsigned)v) << 16;
  return x.f;
}
__device__ __forceinline__ void gload_lds16(const u16* g, u16* l) {
  __builtin_amdgcn_global_load_lds((__attribute__((address_space(1))) void*)g,
                                   (__attribute__((address_space(3))) void*)l,
                                   16, 0, 0);
}
__device__ __forceinline__ unsigned cvtpk(float lo, float hi) {
  unsigned r;
  asm("v_cvt_pk_bf16_f32 %0, %1, %2" : "=v"(r) : "v"(lo), "v"(hi));
  return r;
}
#if __has_builtin(__builtin_amdgcn_mfma_f32_16x16x16bf16_1k)
__device__ __forceinline__ f32x4 mfma16(s16x4 a, s16x4 b, f32x4 c) {
  return __builtin_amdgcn_mfma_f32_16x16x16bf16_1k(a, b, c, 0, 0, 0);
}
#else
__device__ __forceinline__ f32x4 mfma16(s16x4 a, s16x4 b, f32x4 c) {
  asm("v_mfma_f32_16x16x16_bf16 %0, %1, %2, %0" : "+v"(c) : "v"(a), "v"(b));
  return c;
}
#endif

#define SBAR() do { __builtin_amdgcn_sched_barrier(0); \
                    __builtin_amdgcn_s_barrier();      \
                    __builtin_amdgcn_sched_barrier(0); } while (0)

// ---- one-launch prep: all fp32->bf16 converts + RoPE cos/sin table ----
#define PB_X   8192
#define PB_WQ  (PB_X + 4096)
#define PB_WK  (PB_WQ + 1024)
#define PB_WV  (PB_WK + 1024)
#define PB_WO  (PB_WV + 4096)
#define PB_CS  (PB_WO + 512)
__global__ void k_prep(const float* __restrict__ x,
                       const float* __restrict__ Wq, const float* __restrict__ Wk,
                       const float* __restrict__ Wv, const float* __restrict__ Wo,
                       u16* __restrict__ xb, u16* __restrict__ Wqkvb,
                       u16* __restrict__ Wob, float* __restrict__ cs)
{
  const int bid = blockIdx.x, tid = threadIdx.x;
  const float* src; u16* dst; int i;
  if (bid < PB_X)       { i = bid * 256 + tid;            src = x;  dst = xb; }
  else if (bid < PB_WQ) { i = (bid - PB_X) * 256 + tid;   src = Wq; dst = Wqkvb; }
  else if (bid < PB_WK) { i = (bid - PB_WQ) * 256 + tid;  src = Wk; dst = Wqkvb + (size_t)2048 * HID; }
  else if (bid < PB_WV) { i = (bid - PB_WK) * 256 + tid;  src = Wv; dst = Wqkvb + (size_t)2560 * HID; }
  else if (bid < PB_WO) { i = (bid - PB_WV) * 256 + tid;  src = Wo; dst = Wob; }
  else {
    const int p = (bid - PB_WO) * 256 + tid;
    const int s = p >> 6, j = p & 63;
    float inv = expf(-(float)j * 0.14391156831212787f);
    float ang = (float)s * inv;
    float c, sn; sincosf(ang, &sn, &c);
    cs[p * 2 + 0] = c; cs[p * 2 + 1] = sn;
    return;
  }
  float4 v = ((const float4*)src)[i];
  ushort4 o;
  o.x = f2b(v.x); o.y = f2b(v.y); o.z = f2b(v.z); o.w = f2b(v.w);
  ((ushort4*)dst)[i] = o;
}

// ======================================================================
// 256x192-tile 8-phase GEMM (QKV): grid 16x16 = 256 blocks = 1/CU.
// ======================================================================
#define MFMA_G3(AV, NLO, NHI, MO)                                             \
  __builtin_amdgcn_s_setprio(1);                                              \
  _Pragma("unroll") for (int kk = 0; kk < 2; ++kk)                            \
  _Pragma("unroll") for (int mm = 0; mm < 4; ++mm)                            \
  _Pragma("unroll") for (int nn = (NLO); nn <= (NHI); ++nn)                   \
    acc[(MO) + mm][nn] = __builtin_amdgcn_mfma_f32_16x16x32_bf16(             \
        AV[kk][mm], bfr[kk][nn], acc[(MO) + mm][nn], 0, 0, 0);                \
  __builtin_amdgcn_s_setprio(0);

__global__ __launch_bounds__(512, 1) void k_gemm_qkv(
    const u16* __restrict__ A, const u16* __restrict__ Bm,
    u16* __restrict__ C, int M, int N, int K)
{
  __shared__ u16 AL[2][2][8192];   // 64 KB
  __shared__ u16 BL[2][12288];     // 48 KB
  const int tid = threadIdx.x;
  const int wave = tid >> 6, lane = tid & 63;
  const int l15 = lane & 15, l4 = lane >> 4;
  const int wr = wave >> 2, wc = wave & 3;   // 2 M x 4 N
  const int gx = gridDim.x;                  // 16 = N/192
  const int nwg = gx * gridDim.y;            // 256
  int bid = blockIdx.y * gx + blockIdx.x;
  bid = (bid & 7) * (nwg >> 3) + (bid >> 3);
  const int col0 = (bid % gx) * 192, row0 = (bid / gx) * 256;

  int soA[2], dA[2], soB[3], dB[3];
#pragma unroll
  for (int li = 0; li < 3; ++li) {
    const int D = (li * 512 + tid) * 16;
    const int off_p = D & 1023, si = D >> 10;
    const int off_l = off_p ^ (((off_p >> 9) & 1) << 5);
    const int R = si >> 1, Cc = si & 1;
    const int row = R * 16 + (off_l >> 6);
    const int colb = Cc * 64 + (off_l & 63);
    const int so = row * K + (colb >> 1);
    if (li < 2) { soA[li] = so; dA[li] = D; }
    soB[li] = so; dB[li] = D;
  }
  const int laneoff = (l15 * 64 + l4 * 16) ^ ((l15 >> 3) << 5);

  auto stageA = [&](int grow0, int kb, u16* lds) {
#pragma unroll
    for (int li = 0; li < 2; ++li)
      gload_lds16(A + (size_t)grow0 * K + kb + soA[li],
                  (u16*)((char*)lds + dA[li]));
  };
  auto stageB = [&](int kb, u16* lds) {
#pragma unroll
    for (int li = 0; li < 3; ++li)
      gload_lds16(Bm + (size_t)col0 * K + kb + soB[li],
                  (u16*)((char*)lds + dB[li]));
  };

  f32x4 acc[8][3];
#pragma unroll
  for (int m = 0; m < 8; ++m)
#pragma unroll
    for (int n = 0; n < 3; ++n) acc[m][n] = f32x4{0.f, 0.f, 0.f, 0.f};

  const int nk = K >> 6;
  stageA(row0,       0,  &AL[0][0][0]);
  stageA(row0 + 128, 0,  &AL[0][1][0]);
  stageB(0, &BL[0][0]);
  stageA(row0,       64, &AL[1][0][0]);
  stageA(row0 + 128, 64, &AL[1][1][0]);
  asm volatile("s_waitcnt vmcnt(4)" ::: "memory");
  SBAR();

  for (int t = 0; t < nk; ++t) {
    const int bi = t & 1;
    const bool sB = (t + 1 < nk);
    const bool sA = (t + 2 < nk);
    const char* Ab = (const char*)&AL[bi][wr][0];
    const char* Bb = (const char*)&BL[bi][0] + wc * 6144;
    bf16x8 a0[2][4], a1[2][4], bfr[2][3];
#pragma unroll
    for (int kk = 0; kk < 2; ++kk)
#pragma unroll
      for (int m = 0; m < 4; ++m)
        a0[kk][m] = *(const bf16x8*)(Ab + m * 2048 + kk * 1024 + laneoff);
#pragma unroll
    for (int kk = 0; kk < 2; ++kk)
#pragma unroll
      for (int n = 0; n < 3; ++n)
        bfr[kk][n] = *(const bf16x8*)(Bb + n * 2048 + kk * 1024 + laneoff);
    if (sB) stageB((t + 1) * 64, &BL[bi ^ 1][0]);
    SBAR();
    MFMA_G3(a0, 0, 1, 0);
    SBAR();
#pragma unroll
    for (int kk = 0; kk < 2; ++kk)
#pragma unroll
      for (int m = 0; m < 4; ++m)
        a1[kk][m] = *(const bf16x8*)(Ab + (m + 4) * 2048 + kk * 1024 + laneoff);
    SBAR();
    MFMA_G3(a1, 0, 1, 4);
    SBAR();
    if (sA) stageA(row0, (t + 2) * 64, &AL[bi][0][0]);
    SBAR();
    MFMA_G3(a1, 2, 2, 4);
    SBAR();
    if (sA) {
      stageA(row0 + 128, (t + 2) * 64, &AL[bi][1][0]);
      asm volatile("s_waitcnt vmcnt(4)" ::: "memory");
    } else if (sB) {
      asm volatile("s_waitcnt vmcnt(0)" ::: "memory");
    }
    SBAR();
    MFMA_G3(a0, 2, 2, 0);
    SBAR();
  }

#pragma unroll
  for (int m = 0; m < 8; ++m) {
    const int r = row0 + wr * 128 + m * 16 + l4 * 4;
#pragma unroll
    for (int n = 0; n < 3; ++n) {
      const int c = col0 + wc * 48 + n * 16 + l15;
#pragma unroll
      for (int j = 0; j < 4; ++j)
        C[(size_t)(r + j) * N + c] = f2b(acc[m][n][j]);
    }
  }
}

// ======================================================================
// 256x128-tile 8-phase GEMM (out-proj): grid 16x16 = 256 blocks = 1/CU.
// ======================================================================
#define MFMA_GRP2(AV, BV, MO, NO)                                             \
  __builtin_amdgcn_s_setprio(1);                                              \
  _Pragma("unroll") for (int kk = 0; kk < 2; ++kk)                            \
  _Pragma("unroll") for (int mm = 0; mm < 2; ++mm)                            \
  _Pragma("unroll") for (int nn = 0; nn < 2; ++nn)                            \
    acc[(MO) + mm][(NO) + nn] = __builtin_amdgcn_mfma_f32_16x16x32_bf16(      \
        AV[kk][mm], BV[kk][nn], acc[(MO) + mm][(NO) + nn], 0, 0, 0);          \
  __builtin_amdgcn_s_setprio(0);

__global__ __launch_bounds__(512, 1) void k_gemm_op(
    const u16* __restrict__ A, const u16* __restrict__ Bm,
    float* __restrict__ C, int M, int N, int K)
{
  __shared__ u16 AL[2][2][8192];   // 64 KB
  __shared__ u16 BL[2][8192];      // 32 KB
  const int tid = threadIdx.x;
  const int wave = tid >> 6, lane = tid & 63;
  const int l15 = lane & 15, l4 = lane >> 4;
  const int wr = wave >> 1, wc = wave & 1;
  const int gx = gridDim.x;
  const int nwg = gx * gridDim.y;
  int bid = blockIdx.y * gx + blockIdx.x;
  bid = (bid & 7) * (nwg >> 3) + (bid >> 3);
  const int col0 = (bid % gx) * 128, row0 = (bid / gx) * 256;

  int srcOff[2], dstD[2];
#pragma unroll
  for (int li = 0; li < 2; ++li) {
    const int D = (li * 512 + tid) * 16;
    const int off_p = D & 1023, si = D >> 10;
    const int off_l = off_p ^ (((off_p >> 9) & 1) << 5);
    const int R = si >> 1, Cc = si & 1;
    const int row = R * 16 + (off_l >> 6);
    const int colb = Cc * 64 + (off_l & 63);
    srcOff[li] = row * K + (colb >> 1);
    dstD[li] = D;
  }
  const int laneoff = (l15 * 64 + l4 * 16) ^ ((l15 >> 3) << 5);

  auto stage = [&](const u16* __restrict__ G, int grow0, int kb, u16* lds) {
#pragma unroll
    for (int li = 0; li < 2; ++li)
      gload_lds16(G + (size_t)grow0 * K + kb + srcOff[li],
                  (u16*)((char*)lds + dstD[li]));
  };

  f32x4 acc[4][4];
#pragma unroll
  for (int m = 0; m < 4; ++m)
#pragma unroll
    for (int n = 0; n < 4; ++n) acc[m][n] = f32x4{0.f, 0.f, 0.f, 0.f};

  const int nk = K >> 6;
  stage(A,  row0,       0,  &AL[0][0][0]);
  stage(A,  row0 + 128, 0,  &AL[0][1][0]);
  stage(Bm, col0,       0,  &BL[0][0]);
  stage(A,  row0,       64, &AL[1][0][0]);
  stage(A,  row0 + 128, 64, &AL[1][1][0]);
  asm volatile("s_waitcnt vmcnt(4)" ::: "memory");
  SBAR();

  for (int t = 0; t < nk; ++t) {
    const int bi = t & 1;
    const bool sB = (t + 1 < nk);
    const bool sA = (t + 2 < nk);
    const char* Ab = (const char*)&AL[bi][wr >> 1][0];
    const int am = (wr & 1) * 4;
    const char* Bb = (const char*)&BL[bi][0];
    const int bn = wc * 4;
    bf16x8 a0[2][2], a1[2][2], b0[2][2], b1[2][2];
#pragma unroll
    for (int kk = 0; kk < 2; ++kk)
#pragma unroll
      for (int m = 0; m < 2; ++m)
        a0[kk][m] = *(const bf16x8*)(Ab + (am + m) * 2048 + kk * 1024 + laneoff);
#pragma unroll
    for (int kk = 0; kk < 2; ++kk)
#pragma unroll
      for (int n = 0; n < 2; ++n)
        b0[kk][n] = *(const bf16x8*)(Bb + (bn + n) * 2048 + kk * 1024 + laneoff);
    if (sB) stage(Bm, col0, (t + 1) * 64, &BL[bi ^ 1][0]);
    SBAR();
    MFMA_GRP2(a0, b0, 0, 0);
    SBAR();
#pragma unroll
    for (int kk = 0; kk < 2; ++kk)
#pragma unroll
      for (int m = 0; m < 2; ++m)
        a1[kk][m] = *(const bf16x8*)(Ab + (am + 2 + m) * 2048 + kk * 1024 + laneoff);
    SBAR();
    MFMA_GRP2(a1, b0, 2, 0);
    SBAR();
#pragma unroll
    for (int kk = 0; kk < 2; ++kk)
#pragma unroll
      for (int n = 0; n < 2; ++n)
        b1[kk][n] = *(const bf16x8*)(Bb + (bn + 2 + n) * 2048 + kk * 1024 + laneoff);
    if (sA) stage(A, row0, (t + 2) * 64, &AL[bi][0][0]);
    SBAR();
    MFMA_GRP2(a1, b1, 2, 2);
    SBAR();
    if (sA) {
      stage(A, row0 + 128, (t + 2) * 64, &AL[bi][1][0]);
      asm volatile("s_waitcnt vmcnt(4)" ::: "memory");
    } else if (sB) {
      asm volatile("s_waitcnt vmcnt(0)" ::: "memory");
    }
    SBAR();
    MFMA_GRP2(a0, b1, 0, 2);
    SBAR();
  }

#pragma unroll
  for (int m = 0; m < 4; ++m) {
    const int r = row0 + wr * 64 + m * 16 + l4 * 4;
#pragma unroll
    for (int n = 0; n < 4; ++n) {
      const int c = col0 + wc * 64 + n * 16 + l15;
#pragma unroll
      for (int j = 0; j < 4; ++j)
        C[(size_t)(r + j) * N + c] = acc[m][n][j];
    }
  }
}

// ---- fused RoPE (Q pre-scaled by scale*log2e) + K RoPE + V transpose ----
__global__ __launch_bounds__(256) void k_ropev(
    const u16* __restrict__ qkv, const float* __restrict__ cs,
    u16* __restrict__ Qr, u16* __restrict__ Kr, u16* __restrict__ Vt)
{
  const int blk = blockIdx.x;            // b*256 + (s>>3)
  const int b = blk >> 8, s0 = (blk & 255) << 3;
  const int tid = threadIdx.x;
  const float S2 = 0.08838834764831845f * 1.4426950408889634f;
#pragma unroll
  for (int p = tid; p < 1024; p += 256) {
    const int s = p >> 7, rem = p & 127, h = rem >> 3, j8 = (rem & 7) * 8;
    const int sg = s0 + s;
    const u16* src = qkv + (size_t)(b * S_LEN + sg) * QKV_N + h * 128 + j8;
    union { uint4 v; u16 u[8]; } lo, hi, olo, ohi;
    lo.v = *(const uint4*)(src);
    hi.v = *(const uint4*)(src + 64);
    const float* cp = cs + (size_t)(sg * 64 + j8) * 2;
#pragma unroll
    for (int k = 0; k < 8; ++k) {
      const float c = cp[k * 2], sn = cp[k * 2 + 1];
      const float x0 = b2f(lo.u[k]), x1 = b2f(hi.u[k]);
      olo.u[k] = f2b((x0 * c - x1 * sn) * S2);
      ohi.u[k] = f2b((x1 * c + x0 * sn) * S2);
    }
    u16* dst = Qr + ((size_t)(b * NHEADS + h) * S_LEN + sg) * HDIM + j8;
    *(uint4*)(dst) = olo.v;
    *(uint4*)(dst + 64) = ohi.v;
  }
  {
    const int p = tid;
    const int s = p >> 5, rem = p & 31, h = rem >> 3, j8 = (rem & 7) * 8;
    const int sg = s0 + s;
    const u16* src = qkv + (size_t)(b * S_LEN + sg) * QKV_N + 2048 + h * 128 + j8;
    union { uint4 v; u16 u[8]; } lo, hi, olo, ohi;
    lo.v = *(const uint4*)(src);
    hi.v = *(const uint4*)(src + 64);
    const float* cp = cs + (size_t)(sg * 64 + j8) * 2;
#pragma unroll
    for (int k = 0; k < 8; ++k) {
      const float c = cp[k * 2], sn = cp[k * 2 + 1];
      const float x0 = b2f(lo.u[k]), x1 = b2f(hi.u[k]);
      olo.u[k] = f2b(x0 * c - x1 * sn);
      ohi.u[k] = f2b(x1 * c + x0 * sn);
    }
    u16* dst = Kr + ((size_t)(b * NKVH + h) * S_LEN + sg) * HDIM + j8;
    *(uint4*)(dst) = olo.v;
    *(uint4*)(dst + 64) = ohi.v;
  }
#pragma unroll
  for (int vi = 0; vi < 2; ++vi) {
    const int idx = vi * 256 + tid, h = idx >> 7, d = idx & 127;
    union { u16 u[8]; uint4 v; } bb;
#pragma unroll
    for (int s = 0; s < 8; ++s)
      bb.u[s] = qkv[(size_t)(b * S_LEN + s0 + s) * QKV_N + 2560 + idx];
    *(uint4*)(Vt + ((size_t)(b * NKVH + h) * HDIM + d) * S_LEN + s0) = bb.v;
  }
}

// ---- flash attention v18: v17 (KVBLK=128, single barrier/iter) with the
// ---- KV loop UNROLLED BY 2 and STATIC buffer assignment, so all 96 LDS
// ---- read addresses per copy are loop-invariant (address CSE/hoisting;
// ---- removes the runtime `cur` ternary that defeated it) ----
__device__ __forceinline__ void attn_qtile(
    int qt,
    const u16* __restrict__ Q, const u16* __restrict__ Kg, const u16* __restrict__ Vg,
    u16* __restrict__ Out, int bh,
    u16* Kl0, u16* Kl1, u16* Vl0, u16* Vl1,
    const int (&ko)[4], const int (&vo)[4],
    int wave, int w4, int lane)
{
  const int l15 = lane & 15, l4 = lane >> 4;
  const int b = bh >> 4, h = bh & 15;
  const int qw0 = qt * 64 + w4 * 16;
  const u16* Qg = Q + ((size_t)bh * S_LEN + qw0) * HDIM;

  bf16x8 qf[4];
#pragma unroll
  for (int kc = 0; kc < 4; ++kc)
    qf[kc] = *(const bf16x8*)(Qg + l15 * HDIM + kc * 32 + l4 * 8);

  f32x4 zero = {0.f, 0.f, 0.f, 0.f};
  f32x4 oacc[8];
#pragma unroll
  for (int i = 0; i < 8; ++i) oacc[i] = zero;
  float m_r = -1e30f, l_p = 0.f;   // per-lane row state for q = qw0 + l15

  const int nt = (qt + 2) >> 1;    // KV tiles of 128
  const int qg = qw0 + l15;

  // prologue: K(0), V(0) into buffer 0 (always)
#pragma unroll
  for (int it = 0; it < 4; ++it)
    gload_lds16(Kg + ko[it], Kl0 + (it * 8 + wave) * 512);
#pragma unroll
  for (int it = 0; it < 4; ++it)
    gload_lds16(Vg + (size_t)vo[it], Vl0 + (it * 8 + wave) * 512);

  // one iteration with STATIC read buffers (Kb,Vb) and prefetch targets (Kn,Vn)
  auto iter = [&](int t, const u16* KbU, const u16* VbU, u16* Kn, u16* Vn) {
    const int kt = t * 128;
    asm volatile("s_waitcnt vmcnt(0)" ::: "memory");
    SBAR();
    const char* Kb = (const char*)KbU;
    const char* Vb = (const char*)VbU;
    // ---- S^T = K Q^T : lane owns q=l15, k = 16n + 4*l4 + j, n=0..7 ----
    f32x4 s[8];
#pragma unroll
    for (int n = 0; n < 8; ++n) s[n] = zero;
    __builtin_amdgcn_s_setprio(1);
#pragma unroll
    for (int n = 0; n < 8; ++n) {
      const int row = n * 16 + l15;
#pragma unroll
      for (int kc = 0; kc < 4; ++kc) {
        const int ab = (row * 256 + kc * 64 + l4 * 16) ^ ((row & 7) << 4);
        bf16x8 kf = *(const bf16x8*)(Kb + ab);
        s[n] = __builtin_amdgcn_mfma_f32_16x16x32_bf16(kf, qf[kc], s[n], 0, 0, 0);
      }
    }
    __builtin_amdgcn_s_setprio(0);
    // ---- prefetch next tile into the OTHER (static) buffers ----
    if (t + 1 < nt) {
      const int ktn = kt + 128;
#pragma unroll
      for (int it = 0; it < 4; ++it)
        gload_lds16(Kg + (size_t)ktn * HDIM + ko[it], Kn + (it * 8 + wave) * 512);
#pragma unroll
      for (int it = 0; it < 4; ++it)
        gload_lds16(Vg + (size_t)vo[it] + ktn, Vn + (it * 8 + wave) * 512);
    }
    // ---- (rare) causal mask ----
    if (kt + 127 > qw0) {
#pragma unroll
      for (int n = 0; n < 8; ++n)
#pragma unroll
        for (int j = 0; j < 4; ++j)
          if (kt + n * 16 + l4 * 4 + j > qg) s[n][j] = -1e30f;
    }
    float pm = s[0][0];
#pragma unroll
    for (int n = 0; n < 8; ++n)
#pragma unroll
      for (int j = 0; j < 4; ++j) pm = fmaxf(pm, s[n][j]);
    // ---- defer-max ----
    if (!__all(pm <= m_r + 11.5416f)) {
      float pf = fmaxf(pm, __shfl_xor(pm, 16, 64));
      pf = fmaxf(pf, __shfl_xor(pf, 32, 64));
      const float mn = fmaxf(m_r, pf);
      const float sc = exp2f(m_r - mn);
      m_r = mn;
      l_p *= sc;
      float scq[4];
#pragma unroll
      for (int j = 0; j < 4; ++j) scq[j] = __shfl(sc, l4 * 4 + j, 64);
#pragma unroll
      for (int nd = 0; nd < 8; ++nd)
#pragma unroll
        for (int j = 0; j < 4; ++j) oacc[nd][j] *= scq[j];
    }
    // ---- P = exp2(s - m), pack to bf16 A-frags ----
    union { unsigned u[2]; s16x4 v; } a[8];
#pragma unroll
    for (int n = 0; n < 8; ++n) {
      const float p0 = exp2f(s[n][0] - m_r);
      const float p1 = exp2f(s[n][1] - m_r);
      const float p2 = exp2f(s[n][2] - m_r);
      const float p3 = exp2f(s[n][3] - m_r);
      l_p += (p0 + p1) + (p2 + p3);
      a[n].u[0] = cvtpk(p0, p1);
      a[n].u[1] = cvtpk(p2, p3);
    }
    // ---- O += P V (V published at this tile's top barrier) ----
    __builtin_amdgcn_s_setprio(1);
#pragma unroll
    for (int nd = 0; nd < 8; ++nd) {
      const int d = nd * 16 + l15;
      const int rowb = d * 256, swz = (d & 7) << 4;
#pragma unroll
      for (int n = 0; n < 8; ++n) {
        const int ab = (rowb + n * 32 + l4 * 8) ^ swz;
        s16x4 vf = *(const s16x4*)(Vb + ab);
        oacc[nd] = mfma16(a[n].v, vf, oacc[nd]);
      }
    }
    __builtin_amdgcn_s_setprio(0);
  };

  // unrolled-by-2 loop: even iters read buf0 / prefetch buf1, odd read buf1
  for (int t = 0; t < nt; t += 2) {
    iter(t, Kl0, Vl0, Kl1, Vl1);
    if (t + 1 < nt) iter(t + 1, Kl1, Vl1, Kl0, Vl0);
  }

  // ---- epilogue ----
  l_p += __shfl_xor(l_p, 16, 64);
  l_p += __shfl_xor(l_p, 32, 64);
  float il[4];
#pragma unroll
  for (int j = 0; j < 4; ++j) il[j] = 1.f / __shfl(l_p, l4 * 4 + j, 64);
  const size_t obase = ((size_t)b * S_LEN + qw0 + l4 * 4) * HID + h * HDIM;
#pragma unroll
  for (int nd = 0; nd < 8; ++nd)
#pragma unroll
    for (int j = 0; j < 4; ++j)
      Out[obase + (size_t)j * HID + nd * 16 + l15] = f2b(oacc[nd][j] * il[j]);
  // all PV reads of this call consumed before any next-call prologue write
  SBAR();
}

__global__ __launch_bounds__(512) void k_attn(
    const u16* __restrict__ Q, const u16* __restrict__ Kr,
    const u16* __restrict__ Vt, u16* __restrict__ Out)
{
  __shared__ u16 Kl[2][128 * 128];   // 64 KB dbuf: [kv][d], XOR ^((kv&7)<<4)
  __shared__ u16 Vl[2][128 * 128];   // 64 KB dbuf: [d][kv], XOR ^((d&7)<<4)
  const int tid = threadIdx.x;
  const int wave = tid >> 6, lane = tid & 63;
  const int bx = blockIdx.x;              // hp*8 + b*4 + kvh : XCD = bx%8
  const int pairi = blockIdx.y;           // pair (31-pairi, pairi): 17 tiles
  const int kvh = bx & 3, b = (bx >> 2) & 1, hp = bx >> 3;
  const int h = kvh * 4 + hp + (wave >> 2) * 2;   // waves 0-3: h, 4-7: h+2
  const int bh = b * NHEADS + h;
  const int w4 = wave & 3;

  const u16* Kg = Kr + (size_t)(b * NKVH + kvh) * S_LEN * HDIM;
  const u16* Vg = Vt + (size_t)(b * NKVH + kvh) * HDIM * S_LEN;

  // staging offsets (rule 21): 32 chunks of 1 KB, c = it*8 + wave
  int ko[4], vo[4];
#pragma unroll
  for (int it = 0; it < 4; ++it) {
    const int c = it * 8 + wave;
    const int L = c * 1024 + lane * 16;
    const int r = L >> 8;  const int w2 = (L & 255) ^ ((r & 7) << 4);
    ko[it] = r * HDIM + (w2 >> 1);
    const int d = L >> 8;  const int wv = (L & 255) ^ ((d & 7) << 4);
    vo[it] = d * S_LEN + (wv >> 1);
  }

  attn_qtile(31 - pairi, Q, Kg, Vg, Out, bh, &Kl[0][0], &Kl[1][0],
             &Vl[0][0], &Vl[1][0], ko, vo, wave, w4, lane);
  attn_qtile(pairi,      Q, Kg, Vg, Out, bh, &Kl[0][0], &Kl[1][0],
             &Vl[0][0], &Vl[1][0], ko, vo, wave, w4, lane);
}

extern "C" void kernel_launch(void* const* d_in, const int* in_sizes, int n_in,
                              void* d_out, int out_size, void* d_ws, size_t ws_size,
                              hipStream_t stream)
{
  const float* x  = (const float*)d_in[0];
  const float* Wq = (const float*)d_in[2];
  const float* Wk = (const float*)d_in[3];
  const float* Wv = (const float*)d_in[4];
  const float* Wo = (const float*)d_in[5];
  float* out = (float*)d_out;

  u16* xb    = (u16*)d_ws;
  u16* Wqkvb = xb    + (size_t)MROWS * HID;
  u16* Wob   = Wqkvb + (size_t)QKV_N * HID;
  u16* qkv   = Wob   + (size_t)HID * HID;
  u16* Qr    = qkv   + (size_t)MROWS * QKV_N;
  u16* Kr    = Qr    + (size_t)BB * NHEADS * S_LEN * HDIM;
  u16* Vt    = Kr    + (size_t)BB * NKVH * S_LEN * HDIM;
  u16* attn  = Vt    + (size_t)BB * NKVH * S_LEN * HDIM;
  float* cs  = (float*)(attn + (size_t)MROWS * HID);

  k_prep<<<dim3(PB_CS), 256, 0, stream>>>(x, Wq, Wk, Wv, Wo, xb, Wqkvb, Wob, cs);
  k_gemm_qkv<<<dim3(QKV_N / 192, MROWS / 256), 512, 0, stream>>>(xb, Wqkvb, qkv, MROWS, QKV_N, HID);
  k_ropev<<<dim3(BB * 256), 256, 0, stream>>>(qkv, cs, Qr, Kr, Vt);
  k_attn<<<dim3(16, 16), 512, 0, stream>>>(Qr, Kr, Vt, attn);
  k_gemm_op<<<dim3(HID / 128, MROWS / 256), 512, 0, stream>>>(attn, Wob, out, MROWS, HID, HID);
}